// Round 6
// baseline (248.099 us; speedup 1.0000x reference)
//
#include <hip/hip_runtime.h>
#include <hip/hip_cooperative_groups.h>
#include <stdint.h>

namespace cg = cooperative_groups;

#define N_ 256
#define H_ 1024
#define BS_ 128

// ---------------- workspace layout (floats) ----------------
// T   : [3][128][1024] @ 0       tanh outputs (f,g,k)
// sk  : [128][1024]    @ 393216  1 - tk^2
// oacc: [3][128][256]  @ 524288  fo/go/ko accumulators
// jacc: [2][128][256]  @ 622592  Jf/JG accumulators
#define WS_T    0
#define WS_SK   393216
#define WS_OACC 524288
#define WS_JACC 622592
#define WS_FLOATS 688128   // 2,752,512 bytes

struct MFParams {
    const float *x;
    const float *Wf1, *bf1, *Wg1, *bg1, *Wk1, *bk1;
    const float *Wf2, *bf2, *Wg2, *bg2, *Wk2, *bk2;
    float *T, *sk, *oacc, *jacc, *out;
};

// ======================= single cooperative mega-kernel =======================
// grid = 256 blocks x 256 threads (1 block/CU), 3 grid.sync()s.
__global__ __launch_bounds__(256) void mega(MFParams p)
{
    cg::grid_group grid = cg::this_grid();
    const int b = blockIdx.x;
    const int t = threadIdx.x;
    __shared__ float smem[2048];   // 8 KB, reused per phase

    // ---------- phase 1: layer1 (blocks 0..191: m x h-tile x 8-row tile) ----
    if (b < 192) {
        const int m  = b >> 6;             // 0..2
        const int ht = (b >> 4) & 3;       // 0..3
        const int rt = b & 15;             // 0..15
        const int r0 = rt * 8;
        const int h  = ht * 256 + t;
        const float* W  = (m == 0) ? p.Wf1 : (m == 1) ? p.Wg1 : p.Wk1;
        const float* b1 = (m == 0) ? p.bf1 : (m == 1) ? p.bg1 : p.bk1;

        #pragma unroll
        for (int rr = 0; rr < 8; ++rr)
            smem[rr * 256 + t] = p.x[(r0 + rr) * N_ + t];
        __syncthreads();

        float acc[8];
        const float bv = b1[h];
        #pragma unroll
        for (int rr = 0; rr < 8; ++rr) acc[rr] = bv;
        const float4* w4 = (const float4*)(W + h * N_);
        #pragma unroll 4
        for (int c = 0; c < 64; ++c) {
            float4 w = w4[c];
            #pragma unroll
            for (int rr = 0; rr < 8; ++rr) {
                float4 a = ((const float4*)(smem + rr * 256))[c];
                acc[rr] += w.x * a.x + w.y * a.y + w.z * a.z + w.w * a.w;
            }
        }
        #pragma unroll
        for (int rr = 0; rr < 8; ++rr) {
            const float v = tanhf(acc[rr]);
            p.T[(m * BS_ + r0 + rr) * H_ + h] = v;
            if (m == 2) p.sk[(r0 + rr) * H_ + h] = 1.0f - v * v;
        }
    } else {
        // blocks 192..255: zero the atomic accumulators (16384 threads)
        const int base = (b - 192) * 256 + t;
        for (int idx = base; idx < 3 * BS_ * N_; idx += 16384) p.oacc[idx] = 0.0f;
        for (int idx = base; idx < 2 * BS_ * N_; idx += 16384) p.jacc[idx] = 0.0f;
    }
    grid.sync();

    // ---------- phase 2: layer2 (blocks 0..191: m x 4-row tile x k-half) ----
    if (b < 192) {
        const int m  = b >> 6;
        const int rt = (b & 63) >> 1;      // 0..31
        const int ks = b & 1;
        const int r0 = rt * 4;
        const int h0 = ks * 512;
        const float* W  = (m == 0) ? p.Wf2 : (m == 1) ? p.Wg2 : p.Wk2;
        const float* b2 = (m == 0) ? p.bf2 : (m == 1) ? p.bg2 : p.bk2;

        for (int u = t; u < 2048; u += 256)
            smem[u] = p.T[(m * BS_ + r0 + (u >> 9)) * H_ + h0 + (u & 511)];
        __syncthreads();

        float acc[4];
        const float bv = (ks == 0) ? b2[t] : 0.0f;
        #pragma unroll
        for (int rr = 0; rr < 4; ++rr) acc[rr] = bv;
        const float4* w4 = (const float4*)(W + t * H_ + h0);
        #pragma unroll 8
        for (int c = 0; c < 128; ++c) {
            float4 w = w4[c];
            #pragma unroll
            for (int rr = 0; rr < 4; ++rr) {
                float4 a = ((const float4*)(smem + (rr << 9)))[c];
                acc[rr] += w.x * a.x + w.y * a.y + w.z * a.z + w.w * a.w;
            }
        }
        #pragma unroll
        for (int rr = 0; rr < 4; ++rr)
            atomicAdd(&p.oacc[(m * BS_ + r0 + rr) * N_ + t], acc[rr]);
    }
    grid.sync();

    // ---------- phase 3: fused v+J (all 256 blocks: 2-row pair x h-quarter) --
    {
        const int rp = b >> 2;             // 0..63
        const int q  = b & 3;
        const int r0 = rp * 2;
        const int h0 = q * 256;
        const int h  = h0 + t;
        float* fos = smem;                 // [2][256]
        float* gos = smem + 512;
        float* sfv = smem + 1024;
        float* sgv = smem + 1536;

        fos[t]       = p.oacc[r0 * N_ + t];
        fos[256 + t] = p.oacc[(r0 + 1) * N_ + t];
        gos[t]       = p.oacc[(BS_ + r0) * N_ + t];
        gos[256 + t] = p.oacc[(BS_ + r0 + 1) * N_ + t];
        __syncthreads();

        float vf0 = 0.f, vf1 = 0.f, vg0 = 0.f, vg1 = 0.f;
        const float* w2c = p.Wk2 + h;      // coalesced over t
        #pragma unroll 8
        for (int i = 0; i < 256; ++i) {
            const float wv = w2c[i * H_];
            vf0 += wv * fos[i];       vf1 += wv * fos[256 + i];
            vg0 += wv * gos[i];       vg1 += wv * gos[256 + i];
        }
        const float s0 = p.sk[r0 * H_ + h], s1 = p.sk[(r0 + 1) * H_ + h];
        sfv[t] = s0 * vf0;  sfv[256 + t] = s1 * vf1;
        sgv[t] = s0 * vg0;  sgv[256 + t] = s1 * vg1;
        __syncthreads();

        float jf0 = 0.f, jf1 = 0.f, jg0 = 0.f, jg1 = 0.f;
        const float* w1c = p.Wk1 + h0 * N_ + t;   // coalesced over t
        #pragma unroll 8
        for (int hh = 0; hh < 256; ++hh) {
            const float wv = w1c[hh * N_];
            jf0 += sfv[hh] * wv;      jf1 += sfv[256 + hh] * wv;
            jg0 += sgv[hh] * wv;      jg1 += sgv[256 + hh] * wv;
        }
        atomicAdd(&p.jacc[r0 * N_ + t], jf0);
        atomicAdd(&p.jacc[(r0 + 1) * N_ + t], jf1);
        atomicAdd(&p.jacc[(BS_ + r0) * N_ + t], jg0);
        atomicAdd(&p.jacc[(BS_ + r0 + 1) * N_ + t], jg1);
    }
    grid.sync();

    // ---------- phase 4: norms + mask + output (blocks 0..127 = row) --------
    if (b < BS_) {
        const int r = b;
        float* red = smem;
        const float fo = p.oacc[r * N_ + t];
        const float go = p.oacc[(BS_ + r) * N_ + t];
        const float ko = p.oacc[(2 * BS_ + r) * N_ + t];
        const float jf = p.jacc[r * N_ + t];
        const float jg = p.jacc[(BS_ + r) * N_ + t];

        float v0 = ko * ko, v1 = jf * jf, v2 = ko * jg;
        #pragma unroll
        for (int o = 32; o > 0; o >>= 1) {
            v0 += __shfl_xor(v0, o, 64);
            v1 += __shfl_xor(v1, o, 64);
            v2 += __shfl_xor(v2, o, 64);
        }
        const int wid = t >> 6;
        if ((t & 63) == 0) {
            red[wid * 3 + 0] = v0;
            red[wid * 3 + 1] = v1;
            red[wid * 3 + 2] = v2;
        }
        __syncthreads();
        const float kn2 = red[0] + red[3] + red[6] + red[9];
        const float jf2 = red[1] + red[4] + red[7] + red[10];
        const float kjg = red[2] + red[5] + red[8] + red[11];

        const float knorm = sqrtf(kn2);
        const float kn4 = kn2 * kn2;
        const float kn8 = kn4 * kn4;
        const float c1 = sqrtf(jf2) - 60.0f * kn8 * knorm;
        const float c2 = kjg - 20.0f * kn8 * kn2;
        const float scale = ((c1 > 1e-8f) || (c2 < -1e-8f)) ? 0.5f : 1.0f;
        p.out[r * N_ + t] = (fo + go) * scale;
    }
}

// ================== fallback path: proven 4-kernel pipeline ==================
__global__ __launch_bounds__(256) void k1_layer1(
    const float* __restrict__ x,
    const float* __restrict__ Wf1, const float* __restrict__ bf1,
    const float* __restrict__ Wg1, const float* __restrict__ bg1,
    const float* __restrict__ Wk1, const float* __restrict__ bk1,
    float* __restrict__ T, float* __restrict__ sk,
    float* __restrict__ oacc, float* __restrict__ jacc)
{
    const int bx = blockIdx.x;          // m*128 + ht*32 + rt  (384 blocks)
    const int m  = bx >> 7;
    const int ht = (bx & 127) >> 5;
    const int rt = bx & 31;
    const int t  = threadIdx.x;
    const int r0 = rt * 4;
    const int h  = ht * 256 + t;

    const int gtid = bx * 256 + t;      // 0..98303
    if (gtid < 3 * BS_ * N_) oacc[gtid] = 0.0f;
    if (gtid < 2 * BS_ * N_) jacc[gtid] = 0.0f;

    const float* W  = (m == 0) ? Wf1 : (m == 1) ? Wg1 : Wk1;
    const float* b1 = (m == 0) ? bf1 : (m == 1) ? bg1 : bk1;

    __shared__ float xs[4][256];
    #pragma unroll
    for (int rr = 0; rr < 4; ++rr)
        xs[rr][t] = x[(r0 + rr) * N_ + t];
    __syncthreads();

    float acc[4];
    const float bv = b1[h];
    acc[0] = acc[1] = acc[2] = acc[3] = bv;
    const float4* w4 = (const float4*)(W + h * N_);
    #pragma unroll 4
    for (int c = 0; c < 64; ++c) {
        float4 w = w4[c];
        #pragma unroll
        for (int rr = 0; rr < 4; ++rr) {
            float4 a = ((const float4*)xs[rr])[c];
            acc[rr] += w.x * a.x + w.y * a.y + w.z * a.z + w.w * a.w;
        }
    }
    #pragma unroll
    for (int rr = 0; rr < 4; ++rr) {
        const float v = tanhf(acc[rr]);
        T[(m * BS_ + r0 + rr) * H_ + h] = v;
        if (m == 2) sk[(r0 + rr) * H_ + h] = 1.0f - v * v;
    }
}

__global__ __launch_bounds__(256) void k2_layer2(
    const float* __restrict__ T,
    const float* __restrict__ Wf2, const float* __restrict__ bf2,
    const float* __restrict__ Wg2, const float* __restrict__ bg2,
    const float* __restrict__ Wk2, const float* __restrict__ bk2,
    float* __restrict__ oacc)
{
    const int bx = blockIdx.x;          // m*128 + rt*4 + ks  (384 blocks)
    const int m  = bx >> 7;
    const int rt = (bx & 127) >> 2;
    const int ks = bx & 3;
    const int t  = threadIdx.x;
    const int r0 = rt * 4;
    const int h0 = ks * 256;

    const float* W  = (m == 0) ? Wf2 : (m == 1) ? Wg2 : Wk2;
    const float* b2 = (m == 0) ? bf2 : (m == 1) ? bg2 : bk2;

    __shared__ float ts[4][256];
    #pragma unroll
    for (int rr = 0; rr < 4; ++rr)
        ts[rr][t] = T[(m * BS_ + r0 + rr) * H_ + h0 + t];
    __syncthreads();

    float acc[4];
    const float bv = (ks == 0) ? b2[t] : 0.0f;
    acc[0] = acc[1] = acc[2] = acc[3] = bv;
    const float4* w4 = (const float4*)(W + t * H_ + h0);
    #pragma unroll 8
    for (int c = 0; c < 64; ++c) {
        float4 w = w4[c];
        #pragma unroll
        for (int rr = 0; rr < 4; ++rr) {
            float4 a = ((const float4*)ts[rr])[c];
            acc[rr] += w.x * a.x + w.y * a.y + w.z * a.z + w.w * a.w;
        }
    }
    #pragma unroll
    for (int rr = 0; rr < 4; ++rr)
        atomicAdd(&oacc[(m * BS_ + r0 + rr) * N_ + t], acc[rr]);
}

__global__ __launch_bounds__(256) void k34_vj(
    const float* __restrict__ Wk1, const float* __restrict__ Wk2,
    const float* __restrict__ oacc, const float* __restrict__ sk,
    float* __restrict__ jacc)
{
    const int r  = blockIdx.x >> 2;
    const int q  = blockIdx.x & 3;
    const int t  = threadIdx.x;
    const int h0 = q * 256;
    const int h  = h0 + t;

    __shared__ float fos[256], gos[256];
    __shared__ float sfv[256], sgv[256];
    fos[t] = oacc[r * N_ + t];
    gos[t] = oacc[(BS_ + r) * N_ + t];
    __syncthreads();

    float vf = 0.f, vg = 0.f;
    const float* w2 = Wk2 + h;
    #pragma unroll 8
    for (int i = 0; i < 256; ++i) {
        const float wv = w2[i * H_];
        vf += wv * fos[i];
        vg += wv * gos[i];
    }
    const float s = sk[r * H_ + h];
    sfv[t] = s * vf;
    sgv[t] = s * vg;
    __syncthreads();

    float aJf = 0.f, aJg = 0.f;
    const float* w1 = Wk1 + h0 * N_ + t;
    #pragma unroll 8
    for (int hh = 0; hh < 256; ++hh) {
        const float wv = w1[hh * N_];
        aJf += sfv[hh] * wv;
        aJg += sgv[hh] * wv;
    }
    atomicAdd(&jacc[r * N_ + t], aJf);
    atomicAdd(&jacc[(BS_ + r) * N_ + t], aJg);
}

__global__ __launch_bounds__(256) void k5_final(
    const float* __restrict__ oacc,
    const float* __restrict__ jacc,
    float* __restrict__ out)
{
    const int r = blockIdx.x;
    const int t = threadIdx.x;
    __shared__ float red[12];

    const float fo = oacc[r * N_ + t];
    const float go = oacc[(BS_ + r) * N_ + t];
    const float ko = oacc[(2 * BS_ + r) * N_ + t];
    const float jf = jacc[r * N_ + t];
    const float jg = jacc[(BS_ + r) * N_ + t];

    float v0 = ko * ko, v1 = jf * jf, v2 = ko * jg;
    #pragma unroll
    for (int o = 32; o > 0; o >>= 1) {
        v0 += __shfl_xor(v0, o, 64);
        v1 += __shfl_xor(v1, o, 64);
        v2 += __shfl_xor(v2, o, 64);
    }
    const int wid = t >> 6;
    if ((t & 63) == 0) {
        red[wid * 3 + 0] = v0;
        red[wid * 3 + 1] = v1;
        red[wid * 3 + 2] = v2;
    }
    __syncthreads();
    const float kn2 = red[0] + red[3] + red[6] + red[9];
    const float jf2 = red[1] + red[4] + red[7] + red[10];
    const float kjg = red[2] + red[5] + red[8] + red[11];

    const float knorm = sqrtf(kn2);
    const float kn4 = kn2 * kn2;
    const float kn8 = kn4 * kn4;
    const float c1 = sqrtf(jf2) - 60.0f * kn8 * knorm;
    const float c2 = kjg - 20.0f * kn8 * kn2;
    const float scale = ((c1 > 1e-8f) || (c2 < -1e-8f)) ? 0.5f : 1.0f;

    out[r * N_ + t] = (fo + go) * scale;
}

extern "C" void kernel_launch(void* const* d_in, const int* in_sizes, int n_in,
                              void* d_out, int out_size, void* d_ws, size_t ws_size,
                              hipStream_t stream) {
    const float* x    = (const float*)d_in[1];
    const float* Wf1  = (const float*)d_in[2];
    const float* bf1v = (const float*)d_in[3];
    const float* Wf2  = (const float*)d_in[4];
    const float* bf2v = (const float*)d_in[5];
    const float* Wg1  = (const float*)d_in[6];
    const float* bg1v = (const float*)d_in[7];
    const float* Wg2  = (const float*)d_in[8];
    const float* bg2v = (const float*)d_in[9];
    const float* Wk1  = (const float*)d_in[10];
    const float* bk1v = (const float*)d_in[11];
    const float* Wk2  = (const float*)d_in[12];
    const float* bk2v = (const float*)d_in[13];
    float* out = (float*)d_out;

    float* ws   = (float*)d_ws;
    float* T    = ws + WS_T;
    float* sk   = ws + WS_SK;
    float* oacc = ws + WS_OACC;
    float* jacc = ws + WS_JACC;

    // ---- preferred: single cooperative mega-kernel ----
    MFParams p;
    p.x = x;
    p.Wf1 = Wf1; p.bf1 = bf1v; p.Wg1 = Wg1; p.bg1 = bg1v;
    p.Wk1 = Wk1; p.bk1 = bk1v;
    p.Wf2 = Wf2; p.bf2 = bf2v; p.Wg2 = Wg2; p.bg2 = bg2v;
    p.Wk2 = Wk2; p.bk2 = bk2v;
    p.T = T; p.sk = sk; p.oacc = oacc; p.jacc = jacc; p.out = out;
    void* args[] = { (void*)&p };

    hipError_t err = hipLaunchCooperativeKernel(
        (const void*)mega, dim3(256), dim3(256), args, 0, stream);
    if (err == hipSuccess) return;
    (void)hipGetLastError();   // clear sticky error, fall back

    // ---- fallback: 4-kernel pipeline (round-3-style 384-block k1/k2) ----
    k1_layer1<<<384, 256, 0, stream>>>(x, Wf1, bf1v, Wg1, bg1v, Wk1, bk1v,
                                       T, sk, oacc, jacc);
    k2_layer2<<<384, 256, 0, stream>>>(T, Wf2, bf2v, Wg2, bg2v, Wk2, bk2v,
                                       oacc);
    k34_vj   <<<512, 256, 0, stream>>>(Wk1, Wk2, oacc, sk, jacc);
    k5_final <<<BS_, 256, 0, stream>>>(oacc, jacc, out);
}

// Round 7
// 136.035 us; speedup vs baseline: 1.8238x; 1.8238x over previous
//
#include <hip/hip_runtime.h>
#include <stdint.h>

#define N_ 256
#define H_ 1024
#define BS_ 128

// ---------------- workspace layout (floats), all plain stores ----------------
// T    : [3][128][1024]     @ 0          tanh outputs (f,g,k)
// sk   : [128][1024]        @ 393216     1 - tk^2
// oacc : [3][128][256]      @ 524288     reduced fo/go/ko
// opart: [16][3][128][256]  @ 622592     layer2 k-split partials
// jpart: [16][2][128][256]  @ 2195456    J h-split partials
#define WS_T     0
#define WS_SK    393216
#define WS_OACC  524288
#define WS_OPART 622592
#define WS_JPART 2195456
#define WS_FLOATS 3244032   // ~13 MB

// ---- K1: layer1. grid = 3m x 16ht(64h) x 16rt(8rows) = 768 blocks ----
__global__ __launch_bounds__(256) void k1_layer1(
    const float* __restrict__ x,
    const float* __restrict__ Wf1, const float* __restrict__ bf1,
    const float* __restrict__ Wg1, const float* __restrict__ bg1,
    const float* __restrict__ Wk1, const float* __restrict__ bk1,
    float* __restrict__ T, float* __restrict__ sk)
{
    const int bx = blockIdx.x;
    const int m  = bx >> 8;            // 0..2
    const int ht = (bx >> 4) & 15;     // 0..15
    const int rt = bx & 15;            // 0..15
    const int t  = threadIdx.x;
    const int h0 = ht * 64;
    const int r0 = rt * 8;

    const float* W  = (m == 0) ? Wf1 : (m == 1) ? Wg1 : Wk1;
    const float* b1 = (m == 0) ? bf1 : (m == 1) ? bg1 : bk1;

    __shared__ float xs[8][256];       // 8 KB
    for (int u = t; u < 2048; u += 256)
        xs[u >> 8][u & 255] = x[(r0 + (u >> 8)) * N_ + (u & 255)];
    __syncthreads();

    // thread: h = h0 + (t&63); rows r0+2*(t>>6), +1  (2 indep chains)
    const int hl = t & 63;
    const int rl = (t >> 6) * 2;
    const int h  = h0 + hl;

    float a0 = b1[h], a1 = a0;
    const float4* w4  = (const float4*)(W + h * N_);
    const float4* xa4 = (const float4*)xs[rl];
    const float4* xb4 = (const float4*)xs[rl + 1];
    #pragma unroll 8
    for (int c = 0; c < 64; ++c) {
        float4 w = w4[c];
        float4 a = xa4[c];
        float4 b = xb4[c];
        a0 += w.x * a.x + w.y * a.y + w.z * a.z + w.w * a.w;
        a1 += w.x * b.x + w.y * b.y + w.z * b.z + w.w * b.w;
    }
    const float v0 = tanhf(a0), v1 = tanhf(a1);
    T[(m * BS_ + r0 + rl) * H_ + h]     = v0;
    T[(m * BS_ + r0 + rl + 1) * H_ + h] = v1;
    if (m == 2) {
        sk[(r0 + rl) * H_ + h]     = 1.0f - v0 * v0;
        sk[(r0 + rl + 1) * H_ + h] = 1.0f - v1 * v1;
    }
}

// ---- K2: layer2 partials. grid = 3m x 16rt(8rows) x 16ks(64k) = 768 ----
__global__ __launch_bounds__(256) void k2_layer2(
    const float* __restrict__ T,
    const float* __restrict__ Wf2, const float* __restrict__ bf2,
    const float* __restrict__ Wg2, const float* __restrict__ bg2,
    const float* __restrict__ Wk2, const float* __restrict__ bk2,
    float* __restrict__ opart)
{
    const int bx = blockIdx.x;
    const int m  = bx >> 8;
    const int rt = (bx >> 4) & 15;
    const int ks = bx & 15;
    const int t  = threadIdx.x;        // output channel i
    const int r0 = rt * 8;
    const int k0 = ks * 64;

    const float* W  = (m == 0) ? Wf2 : (m == 1) ? Wg2 : Wk2;
    const float* b2 = (m == 0) ? bf2 : (m == 1) ? bg2 : bk2;

    __shared__ float ts[8][64];        // 2 KB
    for (int u = t; u < 512; u += 256)
        ts[u >> 6][u & 63] = T[(m * BS_ + r0 + (u >> 6)) * H_ + k0 + (u & 63)];
    __syncthreads();

    float acc[8];
    const float bv = (ks == 0) ? b2[t] : 0.0f;
    #pragma unroll
    for (int r = 0; r < 8; ++r) acc[r] = bv;

    const float4* w4 = (const float4*)(W + t * H_ + k0);
    #pragma unroll 4
    for (int c = 0; c < 16; ++c) {
        float4 w = w4[c];
        #pragma unroll
        for (int r = 0; r < 8; ++r) {
            float4 a = ((const float4*)ts[r])[c];   // wave-uniform: broadcast
            acc[r] += w.x * a.x + w.y * a.y + w.z * a.z + w.w * a.w;
        }
    }
    #pragma unroll
    for (int r = 0; r < 8; ++r)
        opart[((ks * 3 + m) * BS_ + r0 + r) * N_ + t] = acc[r];
}

// ---- K2.5: reduce opart -> oacc. grid = 384 blocks ----
__global__ __launch_bounds__(256) void k25_reduce(
    const float* __restrict__ opart, float* __restrict__ oacc)
{
    const int tid = blockIdx.x * 256 + threadIdx.x;   // 0..98303
    float s = 0.f;
    #pragma unroll
    for (int ks = 0; ks < 16; ++ks)
        s += opart[ks * (3 * BS_ * N_) + tid];
    oacc[tid] = s;
}

// ---- K3: fused v+J partials. grid = 32rp(4rows) x 16q(64h) = 512 ----
__global__ __launch_bounds__(256) void k3_vj(
    const float* __restrict__ Wk1, const float* __restrict__ Wk2,
    const float* __restrict__ oacc, const float* __restrict__ sk,
    float* __restrict__ jpart)
{
    const int rp = blockIdx.x >> 4;    // 0..31
    const int q  = blockIdx.x & 15;    // 0..15
    const int t  = threadIdx.x;
    const int r0 = rp * 4;
    const int h0 = q * 64;

    __shared__ float fos[4][256], gos[4][256];   // 8 KB
    __shared__ float sfv[4][64], sgv[4][64];     // 2 KB
    for (int u = t; u < 1024; u += 256) {
        const int r = u >> 8, i = u & 255;
        fos[r][i] = oacc[(r0 + r) * N_ + i];
        gos[r][i] = oacc[(BS_ + r0 + r) * N_ + i];
    }
    __syncthreads();

    // phase A: v[r][h] = sum_i o[r][i] * Wk2[i][h]; thread = (h=h0+(t&63), r=t>>6)
    {
        const int hl = t & 63;
        const int rl = t >> 6;
        const int h  = h0 + hl;
        float vf = 0.f, vg = 0.f;
        const float* w2 = Wk2 + h;     // lanes coalesced; same addrs across waves
        #pragma unroll 8
        for (int i = 0; i < 256; ++i) {
            const float wv = w2[i * H_];
            vf += wv * fos[rl][i];     // wave-uniform LDS: broadcast
            vg += wv * gos[rl][i];
        }
        const float s = sk[(r0 + rl) * H_ + h];
        sfv[rl][hl] = s * vf;
        sgv[rl][hl] = s * vg;
    }
    __syncthreads();

    // phase B: J[r][j] += sum_hh sfv[r][hh] * Wk1[h0+hh][j]; thread = j
    {
        float jf[4] = {0.f, 0.f, 0.f, 0.f};
        float jg[4] = {0.f, 0.f, 0.f, 0.f};
        const float* w1 = Wk1 + h0 * N_ + t;    // coalesced over t
        #pragma unroll 8
        for (int hh = 0; hh < 64; ++hh) {
            const float wv = w1[hh * N_];
            #pragma unroll
            for (int r = 0; r < 4; ++r) {
                jf[r] += sfv[r][hh] * wv;       // broadcast
                jg[r] += sgv[r][hh] * wv;
            }
        }
        #pragma unroll
        for (int r = 0; r < 4; ++r) {
            jpart[((q * 2 + 0) * BS_ + r0 + r) * N_ + t] = jf[r];
            jpart[((q * 2 + 1) * BS_ + r0 + r) * N_ + t] = jg[r];
        }
    }
}

// ---- K4: reduce jpart + norms + mask + output. grid = 128 ----
__global__ __launch_bounds__(256) void k4_final(
    const float* __restrict__ oacc,
    const float* __restrict__ jpart,
    float* __restrict__ out)
{
    const int r = blockIdx.x;
    const int t = threadIdx.x;
    __shared__ float red[12];

    const float fo = oacc[r * N_ + t];
    const float go = oacc[(BS_ + r) * N_ + t];
    const float ko = oacc[(2 * BS_ + r) * N_ + t];

    float jf = 0.f, jg = 0.f;
    #pragma unroll
    for (int q = 0; q < 16; ++q) {
        jf += jpart[((q * 2 + 0) * BS_ + r) * N_ + t];
        jg += jpart[((q * 2 + 1) * BS_ + r) * N_ + t];
    }

    float v0 = ko * ko, v1 = jf * jf, v2 = ko * jg;
    #pragma unroll
    for (int o = 32; o > 0; o >>= 1) {
        v0 += __shfl_xor(v0, o, 64);
        v1 += __shfl_xor(v1, o, 64);
        v2 += __shfl_xor(v2, o, 64);
    }
    const int wid = t >> 6;
    if ((t & 63) == 0) {
        red[wid * 3 + 0] = v0;
        red[wid * 3 + 1] = v1;
        red[wid * 3 + 2] = v2;
    }
    __syncthreads();
    const float kn2 = red[0] + red[3] + red[6] + red[9];
    const float jf2 = red[1] + red[4] + red[7] + red[10];
    const float kjg = red[2] + red[5] + red[8] + red[11];

    const float knorm = sqrtf(kn2);
    const float kn4 = kn2 * kn2;
    const float kn8 = kn4 * kn4;
    const float c1 = sqrtf(jf2) - 60.0f * kn8 * knorm;
    const float c2 = kjg - 20.0f * kn8 * kn2;
    const float scale = ((c1 > 1e-8f) || (c2 < -1e-8f)) ? 0.5f : 1.0f;

    out[r * N_ + t] = (fo + go) * scale;
}

// ================= fallback: round-2 proven fused kernel =================
__global__ __launch_bounds__(256) void manifold_fused(
    const float* __restrict__ x,
    const float* __restrict__ Wf1, const float* __restrict__ bf1v,
    const float* __restrict__ Wf2, const float* __restrict__ bf2v,
    const float* __restrict__ Wg1, const float* __restrict__ bg1v,
    const float* __restrict__ Wg2, const float* __restrict__ bg2v,
    const float* __restrict__ Wk1, const float* __restrict__ bk1v,
    const float* __restrict__ Wk2, const float* __restrict__ bk2v,
    float* __restrict__ out)
{
    const int b = blockIdx.x;
    const int t = threadIdx.x;
    __shared__ float xs[N_];
    __shared__ float tf[H_], tg[H_], tk[H_], sk[H_];
    __shared__ float fo[N_], go[N_];
    __shared__ float sfv[H_], sgv[H_];
    __shared__ float red[12];

    xs[t] = x[b * N_ + t];
    __syncthreads();
    {
        float acc[12];
        const float4* rows[12];
        #pragma unroll
        for (int m = 0; m < 4; ++m) {
            const int h = t + m * 256;
            rows[m]     = (const float4*)(Wf1 + h * N_);
            rows[4 + m] = (const float4*)(Wg1 + h * N_);
            rows[8 + m] = (const float4*)(Wk1 + h * N_);
            acc[m] = bf1v[h]; acc[4 + m] = bg1v[h]; acc[8 + m] = bk1v[h];
        }
        const float4* xs4 = (const float4*)xs;
        #pragma unroll 2
        for (int c = 0; c < 64; ++c) {
            float4 a = xs4[c];
            #pragma unroll
            for (int r = 0; r < 12; ++r) {
                float4 w = rows[r][c];
                acc[r] += w.x * a.x + w.y * a.y + w.z * a.z + w.w * a.w;
            }
        }
        #pragma unroll
        for (int m = 0; m < 4; ++m) {
            const int h = t + m * 256;
            float vtf = tanhf(acc[m]);
            float vtg = tanhf(acc[4 + m]);
            float vtk = tanhf(acc[8 + m]);
            tf[h] = vtf; tg[h] = vtg; tk[h] = vtk; sk[h] = 1.0f - vtk * vtk;
        }
    }
    __syncthreads();
    float af = bf2v[t], ag = bg2v[t], ak = bk2v[t];
    {
        const float4* rf = (const float4*)(Wf2 + t * H_);
        const float4* rg = (const float4*)(Wg2 + t * H_);
        const float4* rk = (const float4*)(Wk2 + t * H_);
        #pragma unroll 2
        for (int c = 0; c < 256; ++c) {
            float4 wf = rf[c], wg = rg[c], wk = rk[c];
            float4 vf = ((const float4*)tf)[c];
            af += wf.x*vf.x + wf.y*vf.y + wf.z*vf.z + wf.w*vf.w;
            float4 vg = ((const float4*)tg)[c];
            ag += wg.x*vg.x + wg.y*vg.y + wg.z*vg.z + wg.w*vg.w;
            float4 vk = ((const float4*)tk)[c];
            ak += wk.x*vk.x + wk.y*vk.y + wk.z*vk.z + wk.w*vk.w;
        }
    }
    fo[t] = af; go[t] = ag;
    __syncthreads();
    {
        float vf[4] = {0.f,0.f,0.f,0.f}, vg[4] = {0.f,0.f,0.f,0.f};
        const float* base = Wk2 + 4 * t;
        #pragma unroll 4
        for (int i = 0; i < N_; ++i) {
            float4 w = *(const float4*)(base + i * H_);
            float fv = fo[i], gv = go[i];
            vf[0]+=w.x*fv; vf[1]+=w.y*fv; vf[2]+=w.z*fv; vf[3]+=w.w*fv;
            vg[0]+=w.x*gv; vg[1]+=w.y*gv; vg[2]+=w.z*gv; vg[3]+=w.w*gv;
        }
        #pragma unroll
        for (int c = 0; c < 4; ++c) {
            sfv[4*t+c] = sk[4*t+c]*vf[c];
            sgv[4*t+c] = sk[4*t+c]*vg[c];
        }
    }
    __syncthreads();
    float jf = 0.f, jg = 0.f;
    {
        const float* col = Wk1 + t;
        #pragma unroll 4
        for (int c = 0; c < 256; ++c) {
            float4 s4 = ((const float4*)sfv)[c];
            float4 g4 = ((const float4*)sgv)[c];
            const int h = c * 4;
            float w0 = col[(h+0)*N_], w1 = col[(h+1)*N_];
            float w2 = col[(h+2)*N_], w3 = col[(h+3)*N_];
            jf += s4.x*w0 + s4.y*w1 + s4.z*w2 + s4.w*w3;
            jg += g4.x*w0 + g4.y*w1 + g4.z*w2 + g4.w*w3;
        }
    }
    float v0 = ak*ak, v1 = jf*jf, v2 = ak*jg;
    #pragma unroll
    for (int o = 32; o > 0; o >>= 1) {
        v0 += __shfl_xor(v0, o, 64);
        v1 += __shfl_xor(v1, o, 64);
        v2 += __shfl_xor(v2, o, 64);
    }
    const int wid = t >> 6;
    if ((t & 63) == 0) {
        red[wid*3+0] = v0; red[wid*3+1] = v1; red[wid*3+2] = v2;
    }
    __syncthreads();
    const float kn2 = red[0]+red[3]+red[6]+red[9];
    const float jf2 = red[1]+red[4]+red[7]+red[10];
    const float kjg = red[2]+red[5]+red[8]+red[11];
    const float knorm = sqrtf(kn2);
    const float kn4 = kn2*kn2, kn8 = kn4*kn4;
    const float c1 = sqrtf(jf2) - 60.0f*kn8*knorm;
    const float c2 = kjg - 20.0f*kn8*kn2;
    const float scale = ((c1 > 1e-8f) || (c2 < -1e-8f)) ? 0.5f : 1.0f;
    out[b*N_+t] = (af+ag)*scale;
}

extern "C" void kernel_launch(void* const* d_in, const int* in_sizes, int n_in,
                              void* d_out, int out_size, void* d_ws, size_t ws_size,
                              hipStream_t stream) {
    const float* x    = (const float*)d_in[1];
    const float* Wf1  = (const float*)d_in[2];
    const float* bf1v = (const float*)d_in[3];
    const float* Wf2  = (const float*)d_in[4];
    const float* bf2v = (const float*)d_in[5];
    const float* Wg1  = (const float*)d_in[6];
    const float* bg1v = (const float*)d_in[7];
    const float* Wg2  = (const float*)d_in[8];
    const float* bg2v = (const float*)d_in[9];
    const float* Wk1  = (const float*)d_in[10];
    const float* bk1v = (const float*)d_in[11];
    const float* Wk2  = (const float*)d_in[12];
    const float* bk2v = (const float*)d_in[13];
    float* out = (float*)d_out;

    if (ws_size < (size_t)WS_FLOATS * sizeof(float)) {
        manifold_fused<<<BS_, 256, 0, stream>>>(
            x, Wf1, bf1v, Wf2, bf2v, Wg1, bg1v, Wg2, bg2v,
            Wk1, bk1v, Wk2, bk2v, out);
        return;
    }

    float* ws    = (float*)d_ws;
    float* T     = ws + WS_T;
    float* sk    = ws + WS_SK;
    float* oacc  = ws + WS_OACC;
    float* opart = ws + WS_OPART;
    float* jpart = ws + WS_JPART;

    k1_layer1 <<<768, 256, 0, stream>>>(x, Wf1, bf1v, Wg1, bg1v, Wk1, bk1v, T, sk);
    k2_layer2 <<<768, 256, 0, stream>>>(T, Wf2, bf2v, Wg2, bg2v, Wk2, bk2v, opart);
    k25_reduce<<<384, 256, 0, stream>>>(opart, oacc);
    k3_vj     <<<512, 256, 0, stream>>>(Wk1, Wk2, oacc, sk, jpart);
    k4_final  <<<BS_, 256, 0, stream>>>(oacc, jpart, out);
}

// Round 8
// 135.701 us; speedup vs baseline: 1.8283x; 1.0025x over previous
//
#include <hip/hip_runtime.h>
#include <stdint.h>

#define N_ 256
#define H_ 1024
#define BS_ 128

// ---------------- workspace layout (floats), all plain stores ----------------
// sk   : [128][1024]        @ 0          1 - tk^2
// oacc : [3][128][256]      @ 131072     reduced fo/go/ko
// opart: [16][3][128][256]  @ 229376     layer2 k-split partials
// jpart: [16][2][128][256]  @ 1802240    J h-split partials
#define WS_SK    0
#define WS_OACC  131072
#define WS_OPART 229376
#define WS_JPART 1802240
#define WS_FLOATS 2850816   // ~11.4 MB

// ---- K12: fused layer1+layer2-partial. grid = 3m x 16ht x 16rt = 768 ----
// block: model m, h/k-slice ht (64 wide), rows r0..r0+7.
// phase 1: z[h]=x.W1[h,:]+b1 -> tanh -> LDS ts[8][64] (+sk if m==2)
// phase 2: opart[ht] partial of layer2 over this k-slice (LDS broadcast)
__global__ __launch_bounds__(256) void k12_l1l2(
    const float* __restrict__ x,
    const float* __restrict__ Wf1, const float* __restrict__ bf1,
    const float* __restrict__ Wg1, const float* __restrict__ bg1,
    const float* __restrict__ Wk1, const float* __restrict__ bk1,
    const float* __restrict__ Wf2, const float* __restrict__ bf2,
    const float* __restrict__ Wg2, const float* __restrict__ bg2,
    const float* __restrict__ Wk2, const float* __restrict__ bk2,
    float* __restrict__ sk, float* __restrict__ opart)
{
    const int bx = blockIdx.x;
    const int m  = bx >> 8;            // 0..2
    const int ht = (bx >> 4) & 15;     // 0..15  (h-slice = k-slice)
    const int rt = bx & 15;            // 0..15
    const int t  = threadIdx.x;
    const int h0 = ht * 64;
    const int r0 = rt * 8;

    const float* W1 = (m == 0) ? Wf1 : (m == 1) ? Wg1 : Wk1;
    const float* b1 = (m == 0) ? bf1 : (m == 1) ? bg1 : bk1;
    const float* W2 = (m == 0) ? Wf2 : (m == 1) ? Wg2 : Wk2;
    const float* b2 = (m == 0) ? bf2 : (m == 1) ? bg2 : bk2;

    __shared__ float xs[8][256];       // 8 KB
    __shared__ float ts[8][64];        // 2 KB
    for (int u = t; u < 2048; u += 256)
        xs[u >> 8][u & 255] = x[(r0 + (u >> 8)) * N_ + (u & 255)];
    __syncthreads();

    // ---- phase 1: thread = (hl = t&63, row-pair rg = t>>6) ----
    {
        const int hl = t & 63;
        const int rg = (t >> 6) * 2;
        const int h  = h0 + hl;
        float a0 = b1[h], a1 = a0;
        const float4* w4  = (const float4*)(W1 + h * N_);
        const float4* xa4 = (const float4*)xs[rg];
        const float4* xb4 = (const float4*)xs[rg + 1];
        #pragma unroll 8
        for (int c = 0; c < 64; ++c) {
            float4 w = w4[c];
            float4 a = xa4[c];
            float4 b = xb4[c];
            a0 += w.x * a.x + w.y * a.y + w.z * a.z + w.w * a.w;
            a1 += w.x * b.x + w.y * b.y + w.z * b.z + w.w * b.w;
        }
        const float v0 = tanhf(a0), v1 = tanhf(a1);
        ts[rg][hl]     = v0;
        ts[rg + 1][hl] = v1;
        if (m == 2) {
            sk[(r0 + rg) * H_ + h]     = 1.0f - v0 * v0;
            sk[(r0 + rg + 1) * H_ + h] = 1.0f - v1 * v1;
        }
    }
    __syncthreads();

    // ---- phase 2: thread = output channel i; 8-row partial dot over slice ----
    {
        float acc[8];
        const float bv = (ht == 0) ? b2[t] : 0.0f;
        #pragma unroll
        for (int r = 0; r < 8; ++r) acc[r] = bv;

        const float4* w4 = (const float4*)(W2 + t * H_ + h0);
        #pragma unroll 4
        for (int c = 0; c < 16; ++c) {
            float4 w = w4[c];
            #pragma unroll
            for (int r = 0; r < 8; ++r) {
                float4 a = ((const float4*)ts[r])[c];   // wave-uniform broadcast
                acc[r] += w.x * a.x + w.y * a.y + w.z * a.z + w.w * a.w;
            }
        }
        #pragma unroll
        for (int r = 0; r < 8; ++r)
            opart[((ht * 3 + m) * BS_ + r0 + r) * N_ + t] = acc[r];
    }
}

// ---- K25: reduce opart -> oacc. grid = 384 blocks ----
__global__ __launch_bounds__(256) void k25_reduce(
    const float* __restrict__ opart, float* __restrict__ oacc)
{
    const int tid = blockIdx.x * 256 + threadIdx.x;   // 0..98303
    float s = 0.f;
    #pragma unroll
    for (int ks = 0; ks < 16; ++ks)
        s += opart[ks * (3 * BS_ * N_) + tid];
    oacc[tid] = s;
}

// ---- K3: fused v+J partials. grid = 32rp(4rows) x 16q(64h) = 512 ----
__global__ __launch_bounds__(256) void k3_vj(
    const float* __restrict__ Wk1, const float* __restrict__ Wk2,
    const float* __restrict__ oacc, const float* __restrict__ sk,
    float* __restrict__ jpart)
{
    const int rp = blockIdx.x >> 4;    // 0..31
    const int q  = blockIdx.x & 15;    // 0..15
    const int t  = threadIdx.x;
    const int r0 = rp * 4;
    const int h0 = q * 64;

    __shared__ float sfv[4][64], sgv[4][64];     // 2 KB

    // phase A: v[r][h] = sum_i o[r][i]*Wk2[i][h]; thread = (h, r = wave id)
    // o-streams are wave-uniform -> readfirstlane forces s_load_dwordx4
    {
        const int hl = t & 63;
        const int rl = __builtin_amdgcn_readfirstlane(t >> 6);  // 0..3
        const int h  = h0 + hl;
        const float* fo_p = oacc + (r0 + rl) * N_;
        const float* go_p = oacc + (BS_ + r0 + rl) * N_;
        const float* w2   = Wk2 + h;
        float vf = 0.f, vg = 0.f;
        #pragma unroll 8
        for (int c = 0; c < 64; ++c) {
            const float4 of = *(const float4*)(fo_p + 4 * c);   // scalar load
            const float4 og = *(const float4*)(go_p + 4 * c);   // scalar load
            const float w0 = w2[(4 * c + 0) * H_];
            const float w1 = w2[(4 * c + 1) * H_];
            const float w2v = w2[(4 * c + 2) * H_];
            const float w3 = w2[(4 * c + 3) * H_];
            vf += of.x * w0 + of.y * w1 + of.z * w2v + of.w * w3;
            vg += og.x * w0 + og.y * w1 + og.z * w2v + og.w * w3;
        }
        const float s = sk[(r0 + rl) * H_ + h];
        sfv[rl][hl] = s * vf;
        sgv[rl][hl] = s * vg;
    }
    __syncthreads();

    // phase B: J[r][j] = sum_hh sfv[r][hh]*Wk1[h0+hh][j]; thread = j
    {
        float jf[4] = {0.f, 0.f, 0.f, 0.f};
        float jg[4] = {0.f, 0.f, 0.f, 0.f};
        const float* w1 = Wk1 + h0 * N_ + t;    // coalesced over t
        #pragma unroll 4
        for (int c = 0; c < 16; ++c) {
            const float w0 = w1[(4 * c + 0) * N_];
            const float wv1 = w1[(4 * c + 1) * N_];
            const float wv2 = w1[(4 * c + 2) * N_];
            const float wv3 = w1[(4 * c + 3) * N_];
            #pragma unroll
            for (int r = 0; r < 4; ++r) {
                const float4 sf = ((const float4*)sfv[r])[c];   // ds_read_b128
                const float4 sg = ((const float4*)sgv[r])[c];
                jf[r] += sf.x * w0 + sf.y * wv1 + sf.z * wv2 + sf.w * wv3;
                jg[r] += sg.x * w0 + sg.y * wv1 + sg.z * wv2 + sg.w * wv3;
            }
        }
        #pragma unroll
        for (int r = 0; r < 4; ++r) {
            jpart[((q * 2 + 0) * BS_ + r0 + r) * N_ + t] = jf[r];
            jpart[((q * 2 + 1) * BS_ + r0 + r) * N_ + t] = jg[r];
        }
    }
}

// ---- K4: reduce jpart + norms + mask + output. grid = 128 ----
__global__ __launch_bounds__(256) void k4_final(
    const float* __restrict__ oacc,
    const float* __restrict__ jpart,
    float* __restrict__ out)
{
    const int r = blockIdx.x;
    const int t = threadIdx.x;
    __shared__ float red[12];

    const float fo = oacc[r * N_ + t];
    const float go = oacc[(BS_ + r) * N_ + t];
    const float ko = oacc[(2 * BS_ + r) * N_ + t];

    float jf = 0.f, jg = 0.f;
    #pragma unroll
    for (int q = 0; q < 16; ++q) {
        jf += jpart[((q * 2 + 0) * BS_ + r) * N_ + t];
        jg += jpart[((q * 2 + 1) * BS_ + r) * N_ + t];
    }

    float v0 = ko * ko, v1 = jf * jf, v2 = ko * jg;
    #pragma unroll
    for (int o = 32; o > 0; o >>= 1) {
        v0 += __shfl_xor(v0, o, 64);
        v1 += __shfl_xor(v1, o, 64);
        v2 += __shfl_xor(v2, o, 64);
    }
    const int wid = t >> 6;
    if ((t & 63) == 0) {
        red[wid * 3 + 0] = v0;
        red[wid * 3 + 1] = v1;
        red[wid * 3 + 2] = v2;
    }
    __syncthreads();
    const float kn2 = red[0] + red[3] + red[6] + red[9];
    const float jf2 = red[1] + red[4] + red[7] + red[10];
    const float kjg = red[2] + red[5] + red[8] + red[11];

    const float knorm = sqrtf(kn2);
    const float kn4 = kn2 * kn2;
    const float kn8 = kn4 * kn4;
    const float c1 = sqrtf(jf2) - 60.0f * kn8 * knorm;
    const float c2 = kjg - 20.0f * kn8 * kn2;
    const float scale = ((c1 > 1e-8f) || (c2 < -1e-8f)) ? 0.5f : 1.0f;

    out[r * N_ + t] = (fo + go) * scale;
}

// ================= fallback: round-2 proven fused kernel =================
__global__ __launch_bounds__(256) void manifold_fused(
    const float* __restrict__ x,
    const float* __restrict__ Wf1, const float* __restrict__ bf1v,
    const float* __restrict__ Wf2, const float* __restrict__ bf2v,
    const float* __restrict__ Wg1, const float* __restrict__ bg1v,
    const float* __restrict__ Wg2, const float* __restrict__ bg2v,
    const float* __restrict__ Wk1, const float* __restrict__ bk1v,
    const float* __restrict__ Wk2, const float* __restrict__ bk2v,
    float* __restrict__ out)
{
    const int b = blockIdx.x;
    const int t = threadIdx.x;
    __shared__ float xs[N_];
    __shared__ float tf[H_], tg[H_], tk[H_], sk[H_];
    __shared__ float fo[N_], go[N_];
    __shared__ float sfv[H_], sgv[H_];
    __shared__ float red[12];

    xs[t] = x[b * N_ + t];
    __syncthreads();
    {
        float acc[12];
        const float4* rows[12];
        #pragma unroll
        for (int m = 0; m < 4; ++m) {
            const int h = t + m * 256;
            rows[m]     = (const float4*)(Wf1 + h * N_);
            rows[4 + m] = (const float4*)(Wg1 + h * N_);
            rows[8 + m] = (const float4*)(Wk1 + h * N_);
            acc[m] = bf1v[h]; acc[4 + m] = bg1v[h]; acc[8 + m] = bk1v[h];
        }
        const float4* xs4 = (const float4*)xs;
        #pragma unroll 2
        for (int c = 0; c < 64; ++c) {
            float4 a = xs4[c];
            #pragma unroll
            for (int r = 0; r < 12; ++r) {
                float4 w = rows[r][c];
                acc[r] += w.x * a.x + w.y * a.y + w.z * a.z + w.w * a.w;
            }
        }
        #pragma unroll
        for (int m = 0; m < 4; ++m) {
            const int h = t + m * 256;
            float vtf = tanhf(acc[m]);
            float vtg = tanhf(acc[4 + m]);
            float vtk = tanhf(acc[8 + m]);
            tf[h] = vtf; tg[h] = vtg; tk[h] = vtk; sk[h] = 1.0f - vtk * vtk;
        }
    }
    __syncthreads();
    float af = bf2v[t], ag = bg2v[t], ak = bk2v[t];
    {
        const float4* rf = (const float4*)(Wf2 + t * H_);
        const float4* rg = (const float4*)(Wg2 + t * H_);
        const float4* rk = (const float4*)(Wk2 + t * H_);
        #pragma unroll 2
        for (int c = 0; c < 256; ++c) {
            float4 wf = rf[c], wg = rg[c], wk = rk[c];
            float4 vf = ((const float4*)tf)[c];
            af += wf.x*vf.x + wf.y*vf.y + wf.z*vf.z + wf.w*vf.w;
            float4 vg = ((const float4*)tg)[c];
            ag += wg.x*vg.x + wg.y*vg.y + wg.z*vg.z + wg.w*vg.w;
            float4 vk = ((const float4*)tk)[c];
            ak += wk.x*vk.x + wk.y*vk.y + wk.z*vk.z + wk.w*vk.w;
        }
    }
    fo[t] = af; go[t] = ag;
    __syncthreads();
    {
        float vf[4] = {0.f,0.f,0.f,0.f}, vg[4] = {0.f,0.f,0.f,0.f};
        const float* base = Wk2 + 4 * t;
        #pragma unroll 4
        for (int i = 0; i < N_; ++i) {
            float4 w = *(const float4*)(base + i * H_);
            float fv = fo[i], gv = go[i];
            vf[0]+=w.x*fv; vf[1]+=w.y*fv; vf[2]+=w.z*fv; vf[3]+=w.w*fv;
            vg[0]+=w.x*gv; vg[1]+=w.y*gv; vg[2]+=w.z*gv; vg[3]+=w.w*gv;
        }
        #pragma unroll
        for (int c = 0; c < 4; ++c) {
            sfv[4*t+c] = sk[4*t+c]*vf[c];
            sgv[4*t+c] = sk[4*t+c]*vg[c];
        }
    }
    __syncthreads();
    float jf = 0.f, jg = 0.f;
    {
        const float* col = Wk1 + t;
        #pragma unroll 4
        for (int c = 0; c < 256; ++c) {
            float4 s4 = ((const float4*)sfv)[c];
            float4 g4 = ((const float4*)sgv)[c];
            const int h = c * 4;
            float w0 = col[(h+0)*N_], w1 = col[(h+1)*N_];
            float w2 = col[(h+2)*N_], w3 = col[(h+3)*N_];
            jf += s4.x*w0 + s4.y*w1 + s4.z*w2 + s4.w*w3;
            jg += g4.x*w0 + g4.y*w1 + g4.z*w2 + g4.w*w3;
        }
    }
    float v0 = ak*ak, v1 = jf*jf, v2 = ak*jg;
    #pragma unroll
    for (int o = 32; o > 0; o >>= 1) {
        v0 += __shfl_xor(v0, o, 64);
        v1 += __shfl_xor(v1, o, 64);
        v2 += __shfl_xor(v2, o, 64);
    }
    const int wid = t >> 6;
    if ((t & 63) == 0) {
        red[wid*3+0] = v0; red[wid*3+1] = v1; red[wid*3+2] = v2;
    }
    __syncthreads();
    const float kn2 = red[0]+red[3]+red[6]+red[9];
    const float jf2 = red[1]+red[4]+red[7]+red[10];
    const float kjg = red[2]+red[5]+red[8]+red[11];
    const float knorm = sqrtf(kn2);
    const float kn4 = kn2*kn2, kn8 = kn4*kn4;
    const float c1 = sqrtf(jf2) - 60.0f*kn8*knorm;
    const float c2 = kjg - 20.0f*kn8*kn2;
    const float scale = ((c1 > 1e-8f) || (c2 < -1e-8f)) ? 0.5f : 1.0f;
    out[b*N_+t] = (af+ag)*scale;
}

extern "C" void kernel_launch(void* const* d_in, const int* in_sizes, int n_in,
                              void* d_out, int out_size, void* d_ws, size_t ws_size,
                              hipStream_t stream) {
    const float* x    = (const float*)d_in[1];
    const float* Wf1  = (const float*)d_in[2];
    const float* bf1v = (const float*)d_in[3];
    const float* Wf2  = (const float*)d_in[4];
    const float* bf2v = (const float*)d_in[5];
    const float* Wg1  = (const float*)d_in[6];
    const float* bg1v = (const float*)d_in[7];
    const float* Wg2  = (const float*)d_in[8];
    const float* bg2v = (const float*)d_in[9];
    const float* Wk1  = (const float*)d_in[10];
    const float* bk1v = (const float*)d_in[11];
    const float* Wk2  = (const float*)d_in[12];
    const float* bk2v = (const float*)d_in[13];
    float* out = (float*)d_out;

    if (ws_size < (size_t)WS_FLOATS * sizeof(float)) {
        manifold_fused<<<BS_, 256, 0, stream>>>(
            x, Wf1, bf1v, Wf2, bf2v, Wg1, bg1v, Wg2, bg2v,
            Wk1, bk1v, Wk2, bk2v, out);
        return;
    }

    float* ws    = (float*)d_ws;
    float* sk    = ws + WS_SK;
    float* oacc  = ws + WS_OACC;
    float* opart = ws + WS_OPART;
    float* jpart = ws + WS_JPART;

    k12_l1l2  <<<768, 256, 0, stream>>>(x, Wf1, bf1v, Wg1, bg1v, Wk1, bk1v,
                                        Wf2, bf2v, Wg2, bg2v, Wk2, bk2v,
                                        sk, opart);
    k25_reduce<<<384, 256, 0, stream>>>(opart, oacc);
    k3_vj     <<<512, 256, 0, stream>>>(Wk1, Wk2, oacc, sk, jpart);
    k4_final  <<<BS_, 256, 0, stream>>>(oacc, jpart, out);
}

// Round 9
// 135.372 us; speedup vs baseline: 1.8327x; 1.0024x over previous
//
#include <hip/hip_runtime.h>
#include <stdint.h>

#define N_ 256
#define H_ 1024
#define BS_ 128

// ---------------- workspace layout (floats), all plain stores ----------------
// sk   : [128][1024]        @ 0          1 - tk^2
// oacc : [3][128][256]      @ 131072     reduced fo/go/ko
// opart: [16][3][128][256]  @ 229376     layer2 k-split partials
// jpart: [16][2][128][256]  @ 1802240    J h-split partials
#define WS_SK    0
#define WS_OACC  131072
#define WS_OPART 229376
#define WS_JPART 1802240
#define WS_FLOATS 2850816   // ~11.4 MB

// ---- K12: fused layer1+layer2-partial. grid = 768 ----
// XCD swizzle: bx = g + 48*rt, g = m*16+ht (48 weight-sharing groups of 16
// row-tiles). 48 % 8 == 0 -> bx mod 8 == g mod 8: all blocks sharing a weight
// slice land on one XCD (round-robin dispatch), slice stays L2-resident.
__global__ __launch_bounds__(256) void k12_l1l2(
    const float* __restrict__ x,
    const float* __restrict__ Wf1, const float* __restrict__ bf1,
    const float* __restrict__ Wg1, const float* __restrict__ bg1,
    const float* __restrict__ Wk1, const float* __restrict__ bk1,
    const float* __restrict__ Wf2, const float* __restrict__ bf2,
    const float* __restrict__ Wg2, const float* __restrict__ bg2,
    const float* __restrict__ Wk2, const float* __restrict__ bk2,
    float* __restrict__ sk, float* __restrict__ opart)
{
    const int bx = blockIdx.x;
    const int g  = bx % 48;            // weight-sharing group
    const int rt = bx / 48;            // 0..15 row tile
    const int m  = g >> 4;             // 0..2
    const int ht = g & 15;             // 0..15  (h-slice = k-slice)
    const int t  = threadIdx.x;
    const int h0 = ht * 64;
    const int r0 = rt * 8;

    const float* W1 = (m == 0) ? Wf1 : (m == 1) ? Wg1 : Wk1;
    const float* b1 = (m == 0) ? bf1 : (m == 1) ? bg1 : bk1;
    const float* W2 = (m == 0) ? Wf2 : (m == 1) ? Wg2 : Wk2;
    const float* b2 = (m == 0) ? bf2 : (m == 1) ? bg2 : bk2;

    __shared__ float xs[8][256];       // 8 KB
    __shared__ float ts[8][64];        // 2 KB
    for (int u = t; u < 2048; u += 256)
        xs[u >> 8][u & 255] = x[(r0 + (u >> 8)) * N_ + (u & 255)];
    __syncthreads();

    // ---- phase 1: thread = (hl = t&63, row-pair rg = t>>6) ----
    {
        const int hl = t & 63;
        const int rg = (t >> 6) * 2;
        const int h  = h0 + hl;
        float a0 = b1[h], a1 = a0;
        const float4* w4  = (const float4*)(W1 + h * N_);
        const float4* xa4 = (const float4*)xs[rg];
        const float4* xb4 = (const float4*)xs[rg + 1];
        #pragma unroll 8
        for (int c = 0; c < 64; ++c) {
            float4 w = w4[c];
            float4 a = xa4[c];
            float4 b = xb4[c];
            a0 += w.x * a.x + w.y * a.y + w.z * a.z + w.w * a.w;
            a1 += w.x * b.x + w.y * b.y + w.z * b.z + w.w * b.w;
        }
        const float v0 = tanhf(a0), v1 = tanhf(a1);
        ts[rg][hl]     = v0;
        ts[rg + 1][hl] = v1;
        if (m == 2) {
            sk[(r0 + rg) * H_ + h]     = 1.0f - v0 * v0;
            sk[(r0 + rg + 1) * H_ + h] = 1.0f - v1 * v1;
        }
    }
    __syncthreads();

    // ---- phase 2: thread = output channel i; 8-row partial dot over slice ----
    {
        float acc[8];
        const float bv = (ht == 0) ? b2[t] : 0.0f;
        #pragma unroll
        for (int r = 0; r < 8; ++r) acc[r] = bv;

        const float4* w4 = (const float4*)(W2 + t * H_ + h0);
        #pragma unroll 4
        for (int c = 0; c < 16; ++c) {
            float4 w = w4[c];
            #pragma unroll
            for (int r = 0; r < 8; ++r) {
                float4 a = ((const float4*)ts[r])[c];   // wave-uniform broadcast
                acc[r] += w.x * a.x + w.y * a.y + w.z * a.z + w.w * a.w;
            }
        }
        #pragma unroll
        for (int r = 0; r < 8; ++r)
            opart[((ht * 3 + m) * BS_ + r0 + r) * N_ + t] = acc[r];
    }
}

// ---- K25: reduce opart -> oacc. grid = 384 blocks ----
__global__ __launch_bounds__(256) void k25_reduce(
    const float* __restrict__ opart, float* __restrict__ oacc)
{
    const int tid = blockIdx.x * 256 + threadIdx.x;   // 0..98303
    float s = 0.f;
    #pragma unroll
    for (int ks = 0; ks < 16; ++ks)
        s += opart[ks * (3 * BS_ * N_) + tid];
    oacc[tid] = s;
}

// ---- K3: fused v+J partials. grid = 512 ----
// XCD swizzle: bx = q + 16*rp; 16 % 8 == 0 -> bx mod 8 == q mod 8: the 32
// row-blocks sharing the (Wk1,Wk2) h-slice pair stay on one XCD.
__global__ __launch_bounds__(256) void k3_vj(
    const float* __restrict__ Wk1, const float* __restrict__ Wk2,
    const float* __restrict__ oacc, const float* __restrict__ sk,
    float* __restrict__ jpart)
{
    const int q  = blockIdx.x & 15;    // 0..15 h-slice (weight-sharing group)
    const int rp = blockIdx.x >> 4;    // 0..31 row tile
    const int t  = threadIdx.x;
    const int r0 = rp * 4;
    const int h0 = q * 64;

    __shared__ float sfv[4][64], sgv[4][64];     // 2 KB

    // phase A: v[r][h] = sum_i o[r][i]*Wk2[i][h]; thread = (h, r = wave id)
    // o-streams are wave-uniform -> readfirstlane forces s_load_dwordx4
    {
        const int hl = t & 63;
        const int rl = __builtin_amdgcn_readfirstlane(t >> 6);  // 0..3
        const int h  = h0 + hl;
        const float* fo_p = oacc + (r0 + rl) * N_;
        const float* go_p = oacc + (BS_ + r0 + rl) * N_;
        const float* w2   = Wk2 + h;
        float vf = 0.f, vg = 0.f;
        #pragma unroll 8
        for (int c = 0; c < 64; ++c) {
            const float4 of = *(const float4*)(fo_p + 4 * c);   // scalar load
            const float4 og = *(const float4*)(go_p + 4 * c);   // scalar load
            const float w0 = w2[(4 * c + 0) * H_];
            const float w1 = w2[(4 * c + 1) * H_];
            const float w2v = w2[(4 * c + 2) * H_];
            const float w3 = w2[(4 * c + 3) * H_];
            vf += of.x * w0 + of.y * w1 + of.z * w2v + of.w * w3;
            vg += og.x * w0 + og.y * w1 + og.z * w2v + og.w * w3;
        }
        const float s = sk[(r0 + rl) * H_ + h];
        sfv[rl][hl] = s * vf;
        sgv[rl][hl] = s * vg;
    }
    __syncthreads();

    // phase B: J[r][j] = sum_hh sfv[r][hh]*Wk1[h0+hh][j]; thread = j
    {
        float jf[4] = {0.f, 0.f, 0.f, 0.f};
        float jg[4] = {0.f, 0.f, 0.f, 0.f};
        const float* w1 = Wk1 + h0 * N_ + t;    // coalesced over t
        #pragma unroll 4
        for (int c = 0; c < 16; ++c) {
            const float w0 = w1[(4 * c + 0) * N_];
            const float wv1 = w1[(4 * c + 1) * N_];
            const float wv2 = w1[(4 * c + 2) * N_];
            const float wv3 = w1[(4 * c + 3) * N_];
            #pragma unroll
            for (int r = 0; r < 4; ++r) {
                const float4 sf = ((const float4*)sfv[r])[c];   // ds_read_b128
                const float4 sg = ((const float4*)sgv[r])[c];
                jf[r] += sf.x * w0 + sf.y * wv1 + sf.z * wv2 + sf.w * wv3;
                jg[r] += sg.x * w0 + sg.y * wv1 + sg.z * wv2 + sg.w * wv3;
            }
        }
        #pragma unroll
        for (int r = 0; r < 4; ++r) {
            jpart[((q * 2 + 0) * BS_ + r0 + r) * N_ + t] = jf[r];
            jpart[((q * 2 + 1) * BS_ + r0 + r) * N_ + t] = jg[r];
        }
    }
}

// ---- K4: reduce jpart + norms + mask + output. grid = 128 ----
__global__ __launch_bounds__(256) void k4_final(
    const float* __restrict__ oacc,
    const float* __restrict__ jpart,
    float* __restrict__ out)
{
    const int r = blockIdx.x;
    const int t = threadIdx.x;
    __shared__ float red[12];

    const float fo = oacc[r * N_ + t];
    const float go = oacc[(BS_ + r) * N_ + t];
    const float ko = oacc[(2 * BS_ + r) * N_ + t];

    float jf = 0.f, jg = 0.f;
    #pragma unroll
    for (int q = 0; q < 16; ++q) {
        jf += jpart[((q * 2 + 0) * BS_ + r) * N_ + t];
        jg += jpart[((q * 2 + 1) * BS_ + r) * N_ + t];
    }

    float v0 = ko * ko, v1 = jf * jf, v2 = ko * jg;
    #pragma unroll
    for (int o = 32; o > 0; o >>= 1) {
        v0 += __shfl_xor(v0, o, 64);
        v1 += __shfl_xor(v1, o, 64);
        v2 += __shfl_xor(v2, o, 64);
    }
    const int wid = t >> 6;
    if ((t & 63) == 0) {
        red[wid * 3 + 0] = v0;
        red[wid * 3 + 1] = v1;
        red[wid * 3 + 2] = v2;
    }
    __syncthreads();
    const float kn2 = red[0] + red[3] + red[6] + red[9];
    const float jf2 = red[1] + red[4] + red[7] + red[10];
    const float kjg = red[2] + red[5] + red[8] + red[11];

    const float knorm = sqrtf(kn2);
    const float kn4 = kn2 * kn2;
    const float kn8 = kn4 * kn4;
    const float c1 = sqrtf(jf2) - 60.0f * kn8 * knorm;
    const float c2 = kjg - 20.0f * kn8 * kn2;
    const float scale = ((c1 > 1e-8f) || (c2 < -1e-8f)) ? 0.5f : 1.0f;

    out[r * N_ + t] = (fo + go) * scale;
}

// ================= fallback: round-2 proven fused kernel =================
__global__ __launch_bounds__(256) void manifold_fused(
    const float* __restrict__ x,
    const float* __restrict__ Wf1, const float* __restrict__ bf1v,
    const float* __restrict__ Wf2, const float* __restrict__ bf2v,
    const float* __restrict__ Wg1, const float* __restrict__ bg1v,
    const float* __restrict__ Wg2, const float* __restrict__ bg2v,
    const float* __restrict__ Wk1, const float* __restrict__ bk1v,
    const float* __restrict__ Wk2, const float* __restrict__ bk2v,
    float* __restrict__ out)
{
    const int b = blockIdx.x;
    const int t = threadIdx.x;
    __shared__ float xs[N_];
    __shared__ float tf[H_], tg[H_], tk[H_], sk[H_];
    __shared__ float fo[N_], go[N_];
    __shared__ float sfv[H_], sgv[H_];
    __shared__ float red[12];

    xs[t] = x[b * N_ + t];
    __syncthreads();
    {
        float acc[12];
        const float4* rows[12];
        #pragma unroll
        for (int m = 0; m < 4; ++m) {
            const int h = t + m * 256;
            rows[m]     = (const float4*)(Wf1 + h * N_);
            rows[4 + m] = (const float4*)(Wg1 + h * N_);
            rows[8 + m] = (const float4*)(Wk1 + h * N_);
            acc[m] = bf1v[h]; acc[4 + m] = bg1v[h]; acc[8 + m] = bk1v[h];
        }
        const float4* xs4 = (const float4*)xs;
        #pragma unroll 2
        for (int c = 0; c < 64; ++c) {
            float4 a = xs4[c];
            #pragma unroll
            for (int r = 0; r < 12; ++r) {
                float4 w = rows[r][c];
                acc[r] += w.x * a.x + w.y * a.y + w.z * a.z + w.w * a.w;
            }
        }
        #pragma unroll
        for (int m = 0; m < 4; ++m) {
            const int h = t + m * 256;
            float vtf = tanhf(acc[m]);
            float vtg = tanhf(acc[4 + m]);
            float vtk = tanhf(acc[8 + m]);
            tf[h] = vtf; tg[h] = vtg; tk[h] = vtk; sk[h] = 1.0f - vtk * vtk;
        }
    }
    __syncthreads();
    float af = bf2v[t], ag = bg2v[t], ak = bk2v[t];
    {
        const float4* rf = (const float4*)(Wf2 + t * H_);
        const float4* rg = (const float4*)(Wg2 + t * H_);
        const float4* rk = (const float4*)(Wk2 + t * H_);
        #pragma unroll 2
        for (int c = 0; c < 256; ++c) {
            float4 wf = rf[c], wg = rg[c], wk = rk[c];
            float4 vf = ((const float4*)tf)[c];
            af += wf.x*vf.x + wf.y*vf.y + wf.z*vf.z + wf.w*vf.w;
            float4 vg = ((const float4*)tg)[c];
            ag += wg.x*vg.x + wg.y*vg.y + wg.z*vg.z + wg.w*vg.w;
            float4 vk = ((const float4*)tk)[c];
            ak += wk.x*vk.x + wk.y*vk.y + wk.z*vk.z + wk.w*vk.w;
        }
    }
    fo[t] = af; go[t] = ag;
    __syncthreads();
    {
        float vf[4] = {0.f,0.f,0.f,0.f}, vg[4] = {0.f,0.f,0.f,0.f};
        const float* base = Wk2 + 4 * t;
        #pragma unroll 4
        for (int i = 0; i < N_; ++i) {
            float4 w = *(const float4*)(base + i * H_);
            float fv = fo[i], gv = go[i];
            vf[0]+=w.x*fv; vf[1]+=w.y*fv; vf[2]+=w.z*fv; vf[3]+=w.w*fv;
            vg[0]+=w.x*gv; vg[1]+=w.y*gv; vg[2]+=w.z*gv; vg[3]+=w.w*gv;
        }
        #pragma unroll
        for (int c = 0; c < 4; ++c) {
            sfv[4*t+c] = sk[4*t+c]*vf[c];
            sgv[4*t+c] = sk[4*t+c]*vg[c];
        }
    }
    __syncthreads();
    float jf = 0.f, jg = 0.f;
    {
        const float* col = Wk1 + t;
        #pragma unroll 4
        for (int c = 0; c < 256; ++c) {
            float4 s4 = ((const float4*)sfv)[c];
            float4 g4 = ((const float4*)sgv)[c];
            const int h = c * 4;
            float w0 = col[(h+0)*N_], w1 = col[(h+1)*N_];
            float w2 = col[(h+2)*N_], w3 = col[(h+3)*N_];
            jf += s4.x*w0 + s4.y*w1 + s4.z*w2 + s4.w*w3;
            jg += g4.x*w0 + g4.y*w1 + g4.z*w2 + g4.w*w3;
        }
    }
    float v0 = ak*ak, v1 = jf*jf, v2 = ak*jg;
    #pragma unroll
    for (int o = 32; o > 0; o >>= 1) {
        v0 += __shfl_xor(v0, o, 64);
        v1 += __shfl_xor(v1, o, 64);
        v2 += __shfl_xor(v2, o, 64);
    }
    const int wid = t >> 6;
    if ((t & 63) == 0) {
        red[wid*3+0] = v0; red[wid*3+1] = v1; red[wid*3+2] = v2;
    }
    __syncthreads();
    const float kn2 = red[0]+red[3]+red[6]+red[9];
    const float jf2 = red[1]+red[4]+red[7]+red[10];
    const float kjg = red[2]+red[5]+red[8]+red[11];
    const float knorm = sqrtf(kn2);
    const float kn4 = kn2*kn2, kn8 = kn4*kn4;
    const float c1 = sqrtf(jf2) - 60.0f*kn8*knorm;
    const float c2 = kjg - 20.0f*kn8*kn2;
    const float scale = ((c1 > 1e-8f) || (c2 < -1e-8f)) ? 0.5f : 1.0f;
    out[b*N_+t] = (af+ag)*scale;
}

extern "C" void kernel_launch(void* const* d_in, const int* in_sizes, int n_in,
                              void* d_out, int out_size, void* d_ws, size_t ws_size,
                              hipStream_t stream) {
    const float* x    = (const float*)d_in[1];
    const float* Wf1  = (const float*)d_in[2];
    const float* bf1v = (const float*)d_in[3];
    const float* Wf2  = (const float*)d_in[4];
    const float* bf2v = (const float*)d_in[5];
    const float* Wg1  = (const float*)d_in[6];
    const float* bg1v = (const float*)d_in[7];
    const float* Wg2  = (const float*)d_in[8];
    const float* bg2v = (const float*)d_in[9];
    const float* Wk1  = (const float*)d_in[10];
    const float* bk1v = (const float*)d_in[11];
    const float* Wk2  = (const float*)d_in[12];
    const float* bk2v = (const float*)d_in[13];
    float* out = (float*)d_out;

    if (ws_size < (size_t)WS_FLOATS * sizeof(float)) {
        manifold_fused<<<BS_, 256, 0, stream>>>(
            x, Wf1, bf1v, Wf2, bf2v, Wg1, bg1v, Wg2, bg2v,
            Wk1, bk1v, Wk2, bk2v, out);
        return;
    }

    float* ws    = (float*)d_ws;
    float* sk    = ws + WS_SK;
    float* oacc  = ws + WS_OACC;
    float* opart = ws + WS_OPART;
    float* jpart = ws + WS_JPART;

    k12_l1l2  <<<768, 256, 0, stream>>>(x, Wf1, bf1v, Wg1, bg1v, Wk1, bk1v,
                                        Wf2, bf2v, Wg2, bg2v, Wk2, bk2v,
                                        sk, opart);
    k25_reduce<<<384, 256, 0, stream>>>(opart, oacc);
    k3_vj     <<<512, 256, 0, stream>>>(Wk1, Wk2, oacc, sk, jpart);
    k4_final  <<<BS_, 256, 0, stream>>>(oacc, jpart, out);
}

// Round 10
// 131.647 us; speedup vs baseline: 1.8846x; 1.0283x over previous
//
#include <hip/hip_runtime.h>
#include <stdint.h>

#define N_ 256
#define H_ 1024
#define BS_ 128

// ---------------- workspace layout (floats), all plain stores ----------------
// sk   : [128][1024]        @ 0          1 - tk^2
// opart: [16][3][128][256]  @ 131072     layer2 k-split partials
// jpart: [16][2][128][256]  @ 1703936    J h-split partials
#define WS_SK    0
#define WS_OPART 131072
#define WS_JPART 1703936
#define WS_FLOATS 2752512   // ~11 MB

// ---- K12: fused layer1+layer2-partial. grid = 48 groups x 8 row-tiles = 384 ----
// block: (m, 64-wide h/k-slice ht) = weight group g, rows r0..r0+15.
// XCD swizzle: bx = g + 48*rt -> bx%8 == g%8, weight slice stays on one XCD.
// phase 1: z[h]=x.W1[h,:]+b1 -> tanh -> LDS ts[16][64] (+sk if m==2)
// phase 2: opart[ht] = 16-row partial of layer2 over this 64-wide k-slice
__global__ __launch_bounds__(256) void k12_l1l2(
    const float* __restrict__ x,
    const float* __restrict__ Wf1, const float* __restrict__ bf1,
    const float* __restrict__ Wg1, const float* __restrict__ bg1,
    const float* __restrict__ Wk1, const float* __restrict__ bk1,
    const float* __restrict__ Wf2, const float* __restrict__ bf2,
    const float* __restrict__ Wg2, const float* __restrict__ bg2,
    const float* __restrict__ Wk2, const float* __restrict__ bk2,
    float* __restrict__ sk, float* __restrict__ opart)
{
    const int bx = blockIdx.x;
    const int g  = bx % 48;            // weight-sharing group
    const int rt = bx / 48;            // 0..7 row tile (16 rows)
    const int m  = g >> 4;             // 0..2
    const int ht = g & 15;             // 0..15  (h-slice = k-slice)
    const int t  = threadIdx.x;
    const int h0 = ht * 64;
    const int r0 = rt * 16;

    const float* W1 = (m == 0) ? Wf1 : (m == 1) ? Wg1 : Wk1;
    const float* b1 = (m == 0) ? bf1 : (m == 1) ? bg1 : bk1;
    const float* W2 = (m == 0) ? Wf2 : (m == 1) ? Wg2 : Wk2;
    const float* b2 = (m == 0) ? bf2 : (m == 1) ? bg2 : bk2;

    __shared__ float xs[16][256];      // 16 KB
    __shared__ float ts[16][64];       // 4 KB
    for (int u = t; u < 4096; u += 256)
        xs[u >> 8][u & 255] = x[(r0 + (u >> 8)) * N_ + (u & 255)];
    __syncthreads();

    // ---- phase 1: thread = (hl = t&63, row-quad rq = t>>6 -> rows 4rq..4rq+3)
    {
        const int hl = t & 63;
        const int rq = (t >> 6) * 4;
        const int h  = h0 + hl;
        float a0 = b1[h], a1 = a0, a2 = a0, a3 = a0;
        const float4* w4  = (const float4*)(W1 + h * N_);
        const float4* x0 = (const float4*)xs[rq];
        const float4* x1 = (const float4*)xs[rq + 1];
        const float4* x2 = (const float4*)xs[rq + 2];
        const float4* x3 = (const float4*)xs[rq + 3];
        #pragma unroll 8
        for (int c = 0; c < 64; ++c) {
            float4 w = w4[c];
            float4 p = x0[c];                    // broadcast LDS reads
            a0 += w.x * p.x + w.y * p.y + w.z * p.z + w.w * p.w;
            float4 q = x1[c];
            a1 += w.x * q.x + w.y * q.y + w.z * q.z + w.w * q.w;
            float4 r = x2[c];
            a2 += w.x * r.x + w.y * r.y + w.z * r.z + w.w * r.w;
            float4 s = x3[c];
            a3 += w.x * s.x + w.y * s.y + w.z * s.z + w.w * s.w;
        }
        const float v0 = tanhf(a0), v1 = tanhf(a1);
        const float v2 = tanhf(a2), v3 = tanhf(a3);
        ts[rq][hl] = v0; ts[rq + 1][hl] = v1;
        ts[rq + 2][hl] = v2; ts[rq + 3][hl] = v3;
        if (m == 2) {
            sk[(r0 + rq) * H_ + h]     = 1.0f - v0 * v0;
            sk[(r0 + rq + 1) * H_ + h] = 1.0f - v1 * v1;
            sk[(r0 + rq + 2) * H_ + h] = 1.0f - v2 * v2;
            sk[(r0 + rq + 3) * H_ + h] = 1.0f - v3 * v3;
        }
    }
    __syncthreads();

    // ---- phase 2: thread = output channel i; 16-row partial over the slice --
    {
        float acc[16];
        const float bv = (ht == 0) ? b2[t] : 0.0f;
        #pragma unroll
        for (int r = 0; r < 16; ++r) acc[r] = bv;

        const float4* w4 = (const float4*)(W2 + t * H_ + h0);
        #pragma unroll 2
        for (int c = 0; c < 16; ++c) {
            float4 w = w4[c];
            #pragma unroll
            for (int r = 0; r < 16; ++r) {
                float4 a = ((const float4*)ts[r])[c];   // wave-uniform broadcast
                acc[r] += w.x * a.x + w.y * a.y + w.z * a.z + w.w * a.w;
            }
        }
        #pragma unroll
        for (int r = 0; r < 16; ++r)
            opart[((ht * 3 + m) * BS_ + r0 + r) * N_ + t] = acc[r];
    }
}

// ---- K3: opart-reduce + fused v+J partials. grid = 512 ----
// XCD swizzle: bx = q + 16*rp -> blocks sharing the Wk1/Wk2 h-slice co-locate.
__global__ __launch_bounds__(256) void k3_vj(
    const float* __restrict__ Wk1, const float* __restrict__ Wk2,
    const float* __restrict__ opart, const float* __restrict__ sk,
    float* __restrict__ jpart)
{
    const int q  = blockIdx.x & 15;    // 0..15 h-slice
    const int rp = blockIdx.x >> 4;    // 0..31 row tile
    const int t  = threadIdx.x;
    const int r0 = rp * 4;
    const int h0 = q * 64;

    __shared__ float fos[4][256], gos[4][256];   // 8 KB
    __shared__ float sfv[4][64], sgv[4][64];     // 2 KB

    // ---- phase 0: reduce opart -> fos/gos (coalesced over i) ----
    for (int u = t; u < 1024; u += 256) {
        const int r = u >> 8, i = u & 255;
        float s0 = 0.f, s1 = 0.f;
        #pragma unroll
        for (int ks = 0; ks < 16; ++ks) {
            s0 += opart[((ks * 3 + 0) * BS_ + r0 + r) * N_ + i];
            s1 += opart[((ks * 3 + 1) * BS_ + r0 + r) * N_ + i];
        }
        fos[r][i] = s0;
        gos[r][i] = s1;
    }
    __syncthreads();

    // ---- phase A: v[r][h] = sum_i o[r][i]*Wk2[i][h]; thread = (h, r=wave) ----
    {
        const int hl = t & 63;
        const int rl = t >> 6;         // 0..3, wave-uniform
        const int h  = h0 + hl;
        const float* w2 = Wk2 + h;
        float vf = 0.f, vg = 0.f;
        #pragma unroll 8
        for (int c = 0; c < 64; ++c) {
            const float4 of = ((const float4*)fos[rl])[c];   // broadcast b128
            const float4 og = ((const float4*)gos[rl])[c];
            const float w0 = w2[(4 * c + 0) * H_];
            const float w1 = w2[(4 * c + 1) * H_];
            const float w2v = w2[(4 * c + 2) * H_];
            const float w3 = w2[(4 * c + 3) * H_];
            vf += of.x * w0 + of.y * w1 + of.z * w2v + of.w * w3;
            vg += og.x * w0 + og.y * w1 + og.z * w2v + og.w * w3;
        }
        const float s = sk[(r0 + rl) * H_ + h];
        sfv[rl][hl] = s * vf;
        sgv[rl][hl] = s * vg;
    }
    __syncthreads();

    // ---- phase B: J[r][j] = sum_hh sfv[r][hh]*Wk1[h0+hh][j]; thread = j ----
    {
        float jf[4] = {0.f, 0.f, 0.f, 0.f};
        float jg[4] = {0.f, 0.f, 0.f, 0.f};
        const float* w1 = Wk1 + h0 * N_ + t;    // coalesced over t
        #pragma unroll 4
        for (int c = 0; c < 16; ++c) {
            const float w0 = w1[(4 * c + 0) * N_];
            const float wv1 = w1[(4 * c + 1) * N_];
            const float wv2 = w1[(4 * c + 2) * N_];
            const float wv3 = w1[(4 * c + 3) * N_];
            #pragma unroll
            for (int r = 0; r < 4; ++r) {
                const float4 sf = ((const float4*)sfv[r])[c];   // ds_read_b128
                const float4 sg = ((const float4*)sgv[r])[c];
                jf[r] += sf.x * w0 + sf.y * wv1 + sf.z * wv2 + sf.w * wv3;
                jg[r] += sg.x * w0 + sg.y * wv1 + sg.z * wv2 + sg.w * wv3;
            }
        }
        #pragma unroll
        for (int r = 0; r < 4; ++r) {
            jpart[((q * 2 + 0) * BS_ + r0 + r) * N_ + t] = jf[r];
            jpart[((q * 2 + 1) * BS_ + r0 + r) * N_ + t] = jg[r];
        }
    }
}

// ---- K4: reduce opart+jpart + norms + mask + output. grid = 128 ----
__global__ __launch_bounds__(256) void k4_final(
    const float* __restrict__ opart,
    const float* __restrict__ jpart,
    float* __restrict__ out)
{
    const int r = blockIdx.x;
    const int t = threadIdx.x;
    __shared__ float red[12];

    float fo = 0.f, go = 0.f, ko = 0.f;
    #pragma unroll
    for (int ks = 0; ks < 16; ++ks) {
        fo += opart[((ks * 3 + 0) * BS_ + r) * N_ + t];
        go += opart[((ks * 3 + 1) * BS_ + r) * N_ + t];
        ko += opart[((ks * 3 + 2) * BS_ + r) * N_ + t];
    }

    float jf = 0.f, jg = 0.f;
    #pragma unroll
    for (int q = 0; q < 16; ++q) {
        jf += jpart[((q * 2 + 0) * BS_ + r) * N_ + t];
        jg += jpart[((q * 2 + 1) * BS_ + r) * N_ + t];
    }

    float v0 = ko * ko, v1 = jf * jf, v2 = ko * jg;
    #pragma unroll
    for (int o = 32; o > 0; o >>= 1) {
        v0 += __shfl_xor(v0, o, 64);
        v1 += __shfl_xor(v1, o, 64);
        v2 += __shfl_xor(v2, o, 64);
    }
    const int wid = t >> 6;
    if ((t & 63) == 0) {
        red[wid * 3 + 0] = v0;
        red[wid * 3 + 1] = v1;
        red[wid * 3 + 2] = v2;
    }
    __syncthreads();
    const float kn2 = red[0] + red[3] + red[6] + red[9];
    const float jf2 = red[1] + red[4] + red[7] + red[10];
    const float kjg = red[2] + red[5] + red[8] + red[11];

    const float knorm = sqrtf(kn2);
    const float kn4 = kn2 * kn2;
    const float kn8 = kn4 * kn4;
    const float c1 = sqrtf(jf2) - 60.0f * kn8 * knorm;
    const float c2 = kjg - 20.0f * kn8 * kn2;
    const float scale = ((c1 > 1e-8f) || (c2 < -1e-8f)) ? 0.5f : 1.0f;

    out[r * N_ + t] = (fo + go) * scale;
}

// ================= fallback: round-2 proven fused kernel =================
__global__ __launch_bounds__(256) void manifold_fused(
    const float* __restrict__ x,
    const float* __restrict__ Wf1, const float* __restrict__ bf1v,
    const float* __restrict__ Wf2, const float* __restrict__ bf2v,
    const float* __restrict__ Wg1, const float* __restrict__ bg1v,
    const float* __restrict__ Wg2, const float* __restrict__ bg2v,
    const float* __restrict__ Wk1, const float* __restrict__ bk1v,
    const float* __restrict__ Wk2, const float* __restrict__ bk2v,
    float* __restrict__ out)
{
    const int b = blockIdx.x;
    const int t = threadIdx.x;
    __shared__ float xs[N_];
    __shared__ float tf[H_], tg[H_], tk[H_], sk[H_];
    __shared__ float fo[N_], go[N_];
    __shared__ float sfv[H_], sgv[H_];
    __shared__ float red[12];

    xs[t] = x[b * N_ + t];
    __syncthreads();
    {
        float acc[12];
        const float4* rows[12];
        #pragma unroll
        for (int m = 0; m < 4; ++m) {
            const int h = t + m * 256;
            rows[m]     = (const float4*)(Wf1 + h * N_);
            rows[4 + m] = (const float4*)(Wg1 + h * N_);
            rows[8 + m] = (const float4*)(Wk1 + h * N_);
            acc[m] = bf1v[h]; acc[4 + m] = bg1v[h]; acc[8 + m] = bk1v[h];
        }
        const float4* xs4 = (const float4*)xs;
        #pragma unroll 2
        for (int c = 0; c < 64; ++c) {
            float4 a = xs4[c];
            #pragma unroll
            for (int r = 0; r < 12; ++r) {
                float4 w = rows[r][c];
                acc[r] += w.x * a.x + w.y * a.y + w.z * a.z + w.w * a.w;
            }
        }
        #pragma unroll
        for (int m = 0; m < 4; ++m) {
            const int h = t + m * 256;
            float vtf = tanhf(acc[m]);
            float vtg = tanhf(acc[4 + m]);
            float vtk = tanhf(acc[8 + m]);
            tf[h] = vtf; tg[h] = vtg; tk[h] = vtk; sk[h] = 1.0f - vtk * vtk;
        }
    }
    __syncthreads();
    float af = bf2v[t], ag = bg2v[t], ak = bk2v[t];
    {
        const float4* rf = (const float4*)(Wf2 + t * H_);
        const float4* rg = (const float4*)(Wg2 + t * H_);
        const float4* rk = (const float4*)(Wk2 + t * H_);
        #pragma unroll 2
        for (int c = 0; c < 256; ++c) {
            float4 wf = rf[c], wg = rg[c], wk = rk[c];
            float4 vf = ((const float4*)tf)[c];
            af += wf.x*vf.x + wf.y*vf.y + wf.z*vf.z + wf.w*vf.w;
            float4 vg = ((const float4*)tg)[c];
            ag += wg.x*vg.x + wg.y*vg.y + wg.z*vg.z + wg.w*vg.w;
            float4 vk = ((const float4*)tk)[c];
            ak += wk.x*vk.x + wk.y*vk.y + wk.z*vk.z + wk.w*vk.w;
        }
    }
    fo[t] = af; go[t] = ag;
    __syncthreads();
    {
        float vf[4] = {0.f,0.f,0.f,0.f}, vg[4] = {0.f,0.f,0.f,0.f};
        const float* base = Wk2 + 4 * t;
        #pragma unroll 4
        for (int i = 0; i < N_; ++i) {
            float4 w = *(const float4*)(base + i * H_);
            float fv = fo[i], gv = go[i];
            vf[0]+=w.x*fv; vf[1]+=w.y*fv; vf[2]+=w.z*fv; vf[3]+=w.w*fv;
            vg[0]+=w.x*gv; vg[1]+=w.y*gv; vg[2]+=w.z*gv; vg[3]+=w.w*gv;
        }
        #pragma unroll
        for (int c = 0; c < 4; ++c) {
            sfv[4*t+c] = sk[4*t+c]*vf[c];
            sgv[4*t+c] = sk[4*t+c]*vg[c];
        }
    }
    __syncthreads();
    float jf = 0.f, jg = 0.f;
    {
        const float* col = Wk1 + t;
        #pragma unroll 4
        for (int c = 0; c < 256; ++c) {
            float4 s4 = ((const float4*)sfv)[c];
            float4 g4 = ((const float4*)sgv)[c];
            const int h = c * 4;
            float w0 = col[(h+0)*N_], w1 = col[(h+1)*N_];
            float w2 = col[(h+2)*N_], w3 = col[(h+3)*N_];
            jf += s4.x*w0 + s4.y*w1 + s4.z*w2 + s4.w*w3;
            jg += g4.x*w0 + g4.y*w1 + g4.z*w2 + g4.w*w3;
        }
    }
    float v0 = ak*ak, v1 = jf*jf, v2 = ak*jg;
    #pragma unroll
    for (int o = 32; o > 0; o >>= 1) {
        v0 += __shfl_xor(v0, o, 64);
        v1 += __shfl_xor(v1, o, 64);
        v2 += __shfl_xor(v2, o, 64);
    }
    const int wid = t >> 6;
    if ((t & 63) == 0) {
        red[wid*3+0] = v0; red[wid*3+1] = v1; red[wid*3+2] = v2;
    }
    __syncthreads();
    const float kn2 = red[0]+red[3]+red[6]+red[9];
    const float jf2 = red[1]+red[4]+red[7]+red[10];
    const float kjg = red[2]+red[5]+red[8]+red[11];
    const float knorm = sqrtf(kn2);
    const float kn4 = kn2*kn2, kn8 = kn4*kn4;
    const float c1 = sqrtf(jf2) - 60.0f*kn8*knorm;
    const float c2 = kjg - 20.0f*kn8*kn2;
    const float scale = ((c1 > 1e-8f) || (c2 < -1e-8f)) ? 0.5f : 1.0f;
    out[b*N_+t] = (af+ag)*scale;
}

extern "C" void kernel_launch(void* const* d_in, const int* in_sizes, int n_in,
                              void* d_out, int out_size, void* d_ws, size_t ws_size,
                              hipStream_t stream) {
    const float* x    = (const float*)d_in[1];
    const float* Wf1  = (const float*)d_in[2];
    const float* bf1v = (const float*)d_in[3];
    const float* Wf2  = (const float*)d_in[4];
    const float* bf2v = (const float*)d_in[5];
    const float* Wg1  = (const float*)d_in[6];
    const float* bg1v = (const float*)d_in[7];
    const float* Wg2  = (const float*)d_in[8];
    const float* bg2v = (const float*)d_in[9];
    const float* Wk1  = (const float*)d_in[10];
    const float* bk1v = (const float*)d_in[11];
    const float* Wk2  = (const float*)d_in[12];
    const float* bk2v = (const float*)d_in[13];
    float* out = (float*)d_out;

    if (ws_size < (size_t)WS_FLOATS * sizeof(float)) {
        manifold_fused<<<BS_, 256, 0, stream>>>(
            x, Wf1, bf1v, Wf2, bf2v, Wg1, bg1v, Wg2, bg2v,
            Wk1, bk1v, Wk2, bk2v, out);
        return;
    }

    float* ws    = (float*)d_ws;
    float* sk    = ws + WS_SK;
    float* opart = ws + WS_OPART;
    float* jpart = ws + WS_JPART;

    k12_l1l2<<<384, 256, 0, stream>>>(x, Wf1, bf1v, Wg1, bg1v, Wk1, bk1v,
                                      Wf2, bf2v, Wg2, bg2v, Wk2, bk2v,
                                      sk, opart);
    k3_vj   <<<512, 256, 0, stream>>>(Wk1, Wk2, opart, sk, jpart);
    k4_final<<<BS_, 256, 0, stream>>>(opart, jpart, out);
}

// Round 11
// 130.352 us; speedup vs baseline: 1.9033x; 1.0099x over previous
//
#include <hip/hip_runtime.h>
#include <stdint.h>

#define N_ 256
#define H_ 1024
#define BS_ 128

// ---------------- workspace layout (floats), all plain stores ----------------
// sk   : [128][1024]        @ 0          1 - tk^2
// oacc : [3][128][256]      @ 131072     reduced fo/go/ko
// opart: [16][3][128][256]  @ 229376     layer2 k-split partials
// jpart: [16][2][128][256]  @ 1802240    J h-split partials
#define WS_SK    0
#define WS_OACC  131072
#define WS_OPART 229376
#define WS_JPART 1802240
#define WS_FLOATS 2850816   // ~11.4 MB

// ---- K12: fused layer1+layer2-partial. grid = 48 groups x 8 row-tiles = 384 ----
// block: (m, 64-wide h/k-slice ht) = weight group g, rows r0..r0+15.
// XCD swizzle: bx = g + 48*rt -> bx%8 == g%8, weight slice stays on one XCD.
__global__ __launch_bounds__(256) void k12_l1l2(
    const float* __restrict__ x,
    const float* __restrict__ Wf1, const float* __restrict__ bf1,
    const float* __restrict__ Wg1, const float* __restrict__ bg1,
    const float* __restrict__ Wk1, const float* __restrict__ bk1,
    const float* __restrict__ Wf2, const float* __restrict__ bf2,
    const float* __restrict__ Wg2, const float* __restrict__ bg2,
    const float* __restrict__ Wk2, const float* __restrict__ bk2,
    float* __restrict__ sk, float* __restrict__ opart)
{
    const int bx = blockIdx.x;
    const int g  = bx % 48;            // weight-sharing group
    const int rt = bx / 48;            // 0..7 row tile (16 rows)
    const int m  = g >> 4;             // 0..2
    const int ht = g & 15;             // 0..15  (h-slice = k-slice)
    const int t  = threadIdx.x;
    const int h0 = ht * 64;
    const int r0 = rt * 16;

    const float* W1 = (m == 0) ? Wf1 : (m == 1) ? Wg1 : Wk1;
    const float* b1 = (m == 0) ? bf1 : (m == 1) ? bg1 : bk1;
    const float* W2 = (m == 0) ? Wf2 : (m == 1) ? Wg2 : Wk2;
    const float* b2 = (m == 0) ? bf2 : (m == 1) ? bg2 : bk2;

    __shared__ float xs[16][256];      // 16 KB
    __shared__ float ts[16][64];       // 4 KB
    for (int u = t; u < 4096; u += 256)
        xs[u >> 8][u & 255] = x[(r0 + (u >> 8)) * N_ + (u & 255)];
    __syncthreads();

    // ---- phase 1: thread = (hl = t&63, row-quad rq = t>>6 -> rows 4rq..4rq+3)
    {
        const int hl = t & 63;
        const int rq = (t >> 6) * 4;
        const int h  = h0 + hl;
        float a0 = b1[h], a1 = a0, a2 = a0, a3 = a0;
        const float4* w4  = (const float4*)(W1 + h * N_);
        const float4* x0 = (const float4*)xs[rq];
        const float4* x1 = (const float4*)xs[rq + 1];
        const float4* x2 = (const float4*)xs[rq + 2];
        const float4* x3 = (const float4*)xs[rq + 3];
        #pragma unroll 8
        for (int c = 0; c < 64; ++c) {
            float4 w = w4[c];
            float4 p = x0[c];                    // broadcast LDS reads
            a0 += w.x * p.x + w.y * p.y + w.z * p.z + w.w * p.w;
            float4 q = x1[c];
            a1 += w.x * q.x + w.y * q.y + w.z * q.z + w.w * q.w;
            float4 r = x2[c];
            a2 += w.x * r.x + w.y * r.y + w.z * r.z + w.w * r.w;
            float4 s = x3[c];
            a3 += w.x * s.x + w.y * s.y + w.z * s.z + w.w * s.w;
        }
        const float v0 = tanhf(a0), v1 = tanhf(a1);
        const float v2 = tanhf(a2), v3 = tanhf(a3);
        ts[rq][hl] = v0; ts[rq + 1][hl] = v1;
        ts[rq + 2][hl] = v2; ts[rq + 3][hl] = v3;
        if (m == 2) {
            sk[(r0 + rq) * H_ + h]     = 1.0f - v0 * v0;
            sk[(r0 + rq + 1) * H_ + h] = 1.0f - v1 * v1;
            sk[(r0 + rq + 2) * H_ + h] = 1.0f - v2 * v2;
            sk[(r0 + rq + 3) * H_ + h] = 1.0f - v3 * v3;
        }
    }
    __syncthreads();

    // ---- phase 2: thread = output channel i; 16-row partial over the slice --
    {
        float acc[16];
        const float bv = (ht == 0) ? b2[t] : 0.0f;
        #pragma unroll
        for (int r = 0; r < 16; ++r) acc[r] = bv;

        const float4* w4 = (const float4*)(W2 + t * H_ + h0);
        #pragma unroll 2
        for (int c = 0; c < 16; ++c) {
            float4 w = w4[c];
            #pragma unroll
            for (int r = 0; r < 16; ++r) {
                float4 a = ((const float4*)ts[r])[c];   // wave-uniform broadcast
                acc[r] += w.x * a.x + w.y * a.y + w.z * a.z + w.w * a.w;
            }
        }
        #pragma unroll
        for (int r = 0; r < 16; ++r)
            opart[((ht * 3 + m) * BS_ + r0 + r) * N_ + t] = acc[r];
    }
}

// ---- K25: reduce opart -> oacc once. grid = 384 blocks, ~2 us ----
__global__ __launch_bounds__(256) void k25_reduce(
    const float* __restrict__ opart, float* __restrict__ oacc)
{
    const int tid = blockIdx.x * 256 + threadIdx.x;   // 0..98303
    float s = 0.f;
    #pragma unroll
    for (int ks = 0; ks < 16; ++ks)
        s += opart[ks * (3 * BS_ * N_) + tid];
    oacc[tid] = s;
}

// ---- K3: fused v+J partials, reads reduced oacc. grid = 512 ----
// XCD swizzle: bx = q + 16*rp -> blocks sharing the Wk1/Wk2 h-slice co-locate.
__global__ __launch_bounds__(256) void k3_vj(
    const float* __restrict__ Wk1, const float* __restrict__ Wk2,
    const float* __restrict__ oacc, const float* __restrict__ sk,
    float* __restrict__ jpart)
{
    const int q  = blockIdx.x & 15;    // 0..15 h-slice
    const int rp = blockIdx.x >> 4;    // 0..31 row tile
    const int t  = threadIdx.x;
    const int r0 = rp * 4;
    const int h0 = q * 64;

    __shared__ float fos[4][256], gos[4][256];   // 8 KB
    __shared__ float sfv[4][64], sgv[4][64];     // 2 KB

    // stage reduced fo/go rows (coalesced, 4 KB total reads)
    for (int u = t; u < 1024; u += 256) {
        const int r = u >> 8, i = u & 255;
        fos[r][i] = oacc[(r0 + r) * N_ + i];
        gos[r][i] = oacc[(BS_ + r0 + r) * N_ + i];
    }
    __syncthreads();

    // ---- phase A: v[r][h] = sum_i o[r][i]*Wk2[i][h]; thread = (h, r=wave) ----
    {
        const int hl = t & 63;
        const int rl = t >> 6;         // 0..3, wave-uniform
        const int h  = h0 + hl;
        const float* w2 = Wk2 + h;
        float vf = 0.f, vg = 0.f;
        #pragma unroll 8
        for (int c = 0; c < 64; ++c) {
            const float4 of = ((const float4*)fos[rl])[c];   // broadcast b128
            const float4 og = ((const float4*)gos[rl])[c];
            const float w0 = w2[(4 * c + 0) * H_];
            const float w1 = w2[(4 * c + 1) * H_];
            const float w2v = w2[(4 * c + 2) * H_];
            const float w3 = w2[(4 * c + 3) * H_];
            vf += of.x * w0 + of.y * w1 + of.z * w2v + of.w * w3;
            vg += og.x * w0 + og.y * w1 + og.z * w2v + og.w * w3;
        }
        const float s = sk[(r0 + rl) * H_ + h];
        sfv[rl][hl] = s * vf;
        sgv[rl][hl] = s * vg;
    }
    __syncthreads();

    // ---- phase B: J[r][j] = sum_hh sfv[r][hh]*Wk1[h0+hh][j]; thread = j ----
    {
        float jf[4] = {0.f, 0.f, 0.f, 0.f};
        float jg[4] = {0.f, 0.f, 0.f, 0.f};
        const float* w1 = Wk1 + h0 * N_ + t;    // coalesced over t
        #pragma unroll 4
        for (int c = 0; c < 16; ++c) {
            const float w0 = w1[(4 * c + 0) * N_];
            const float wv1 = w1[(4 * c + 1) * N_];
            const float wv2 = w1[(4 * c + 2) * N_];
            const float wv3 = w1[(4 * c + 3) * N_];
            #pragma unroll
            for (int r = 0; r < 4; ++r) {
                const float4 sf = ((const float4*)sfv[r])[c];   // ds_read_b128
                const float4 sg = ((const float4*)sgv[r])[c];
                jf[r] += sf.x * w0 + sf.y * wv1 + sf.z * wv2 + sf.w * wv3;
                jg[r] += sg.x * w0 + sg.y * wv1 + sg.z * wv2 + sg.w * wv3;
            }
        }
        #pragma unroll
        for (int r = 0; r < 4; ++r) {
            jpart[((q * 2 + 0) * BS_ + r0 + r) * N_ + t] = jf[r];
            jpart[((q * 2 + 1) * BS_ + r0 + r) * N_ + t] = jg[r];
        }
    }
}

// ---- K4: reduce jpart + norms + mask + output. grid = 128 ----
__global__ __launch_bounds__(256) void k4_final(
    const float* __restrict__ oacc,
    const float* __restrict__ jpart,
    float* __restrict__ out)
{
    const int r = blockIdx.x;
    const int t = threadIdx.x;
    __shared__ float red[12];

    const float fo = oacc[r * N_ + t];
    const float go = oacc[(BS_ + r) * N_ + t];
    const float ko = oacc[(2 * BS_ + r) * N_ + t];

    float jf = 0.f, jg = 0.f;
    #pragma unroll
    for (int q = 0; q < 16; ++q) {
        jf += jpart[((q * 2 + 0) * BS_ + r) * N_ + t];
        jg += jpart[((q * 2 + 1) * BS_ + r) * N_ + t];
    }

    float v0 = ko * ko, v1 = jf * jf, v2 = ko * jg;
    #pragma unroll
    for (int o = 32; o > 0; o >>= 1) {
        v0 += __shfl_xor(v0, o, 64);
        v1 += __shfl_xor(v1, o, 64);
        v2 += __shfl_xor(v2, o, 64);
    }
    const int wid = t >> 6;
    if ((t & 63) == 0) {
        red[wid * 3 + 0] = v0;
        red[wid * 3 + 1] = v1;
        red[wid * 3 + 2] = v2;
    }
    __syncthreads();
    const float kn2 = red[0] + red[3] + red[6] + red[9];
    const float jf2 = red[1] + red[4] + red[7] + red[10];
    const float kjg = red[2] + red[5] + red[8] + red[11];

    const float knorm = sqrtf(kn2);
    const float kn4 = kn2 * kn2;
    const float kn8 = kn4 * kn4;
    const float c1 = sqrtf(jf2) - 60.0f * kn8 * knorm;
    const float c2 = kjg - 20.0f * kn8 * kn2;
    const float scale = ((c1 > 1e-8f) || (c2 < -1e-8f)) ? 0.5f : 1.0f;

    out[r * N_ + t] = (fo + go) * scale;
}

// ================= fallback: round-2 proven fused kernel =================
__global__ __launch_bounds__(256) void manifold_fused(
    const float* __restrict__ x,
    const float* __restrict__ Wf1, const float* __restrict__ bf1v,
    const float* __restrict__ Wf2, const float* __restrict__ bf2v,
    const float* __restrict__ Wg1, const float* __restrict__ bg1v,
    const float* __restrict__ Wg2, const float* __restrict__ bg2v,
    const float* __restrict__ Wk1, const float* __restrict__ bk1v,
    const float* __restrict__ Wk2, const float* __restrict__ bk2v,
    float* __restrict__ out)
{
    const int b = blockIdx.x;
    const int t = threadIdx.x;
    __shared__ float xs[N_];
    __shared__ float tf[H_], tg[H_], tk[H_], sk[H_];
    __shared__ float fo[N_], go[N_];
    __shared__ float sfv[H_], sgv[H_];
    __shared__ float red[12];

    xs[t] = x[b * N_ + t];
    __syncthreads();
    {
        float acc[12];
        const float4* rows[12];
        #pragma unroll
        for (int m = 0; m < 4; ++m) {
            const int h = t + m * 256;
            rows[m]     = (const float4*)(Wf1 + h * N_);
            rows[4 + m] = (const float4*)(Wg1 + h * N_);
            rows[8 + m] = (const float4*)(Wk1 + h * N_);
            acc[m] = bf1v[h]; acc[4 + m] = bg1v[h]; acc[8 + m] = bk1v[h];
        }
        const float4* xs4 = (const float4*)xs;
        #pragma unroll 2
        for (int c = 0; c < 64; ++c) {
            float4 a = xs4[c];
            #pragma unroll
            for (int r = 0; r < 12; ++r) {
                float4 w = rows[r][c];
                acc[r] += w.x * a.x + w.y * a.y + w.z * a.z + w.w * a.w;
            }
        }
        #pragma unroll
        for (int m = 0; m < 4; ++m) {
            const int h = t + m * 256;
            float vtf = tanhf(acc[m]);
            float vtg = tanhf(acc[4 + m]);
            float vtk = tanhf(acc[8 + m]);
            tf[h] = vtf; tg[h] = vtg; tk[h] = vtk; sk[h] = 1.0f - vtk * vtk;
        }
    }
    __syncthreads();
    float af = bf2v[t], ag = bg2v[t], ak = bk2v[t];
    {
        const float4* rf = (const float4*)(Wf2 + t * H_);
        const float4* rg = (const float4*)(Wg2 + t * H_);
        const float4* rk = (const float4*)(Wk2 + t * H_);
        #pragma unroll 2
        for (int c = 0; c < 256; ++c) {
            float4 wf = rf[c], wg = rg[c], wk = rk[c];
            float4 vf = ((const float4*)tf)[c];
            af += wf.x*vf.x + wf.y*vf.y + wf.z*vf.z + wf.w*vf.w;
            float4 vg = ((const float4*)tg)[c];
            ag += wg.x*vg.x + wg.y*vg.y + wg.z*vg.z + wg.w*vg.w;
            float4 vk = ((const float4*)tk)[c];
            ak += wk.x*vk.x + wk.y*vk.y + wk.z*vk.z + wk.w*vk.w;
        }
    }
    fo[t] = af; go[t] = ag;
    __syncthreads();
    {
        float vf[4] = {0.f,0.f,0.f,0.f}, vg[4] = {0.f,0.f,0.f,0.f};
        const float* base = Wk2 + 4 * t;
        #pragma unroll 4
        for (int i = 0; i < N_; ++i) {
            float4 w = *(const float4*)(base + i * H_);
            float fv = fo[i], gv = go[i];
            vf[0]+=w.x*fv; vf[1]+=w.y*fv; vf[2]+=w.z*fv; vf[3]+=w.w*fv;
            vg[0]+=w.x*gv; vg[1]+=w.y*gv; vg[2]+=w.z*gv; vg[3]+=w.w*gv;
        }
        #pragma unroll
        for (int c = 0; c < 4; ++c) {
            sfv[4*t+c] = sk[4*t+c]*vf[c];
            sgv[4*t+c] = sk[4*t+c]*vg[c];
        }
    }
    __syncthreads();
    float jf = 0.f, jg = 0.f;
    {
        const float* col = Wk1 + t;
        #pragma unroll 4
        for (int c = 0; c < 256; ++c) {
            float4 s4 = ((const float4*)sfv)[c];
            float4 g4 = ((const float4*)sgv)[c];
            const int h = c * 4;
            float w0 = col[(h+0)*N_], w1 = col[(h+1)*N_];
            float w2 = col[(h+2)*N_], w3 = col[(h+3)*N_];
            jf += s4.x*w0 + s4.y*w1 + s4.z*w2 + s4.w*w3;
            jg += g4.x*w0 + g4.y*w1 + g4.z*w2 + g4.w*w3;
        }
    }
    float v0 = ak*ak, v1 = jf*jf, v2 = ak*jg;
    #pragma unroll
    for (int o = 32; o > 0; o >>= 1) {
        v0 += __shfl_xor(v0, o, 64);
        v1 += __shfl_xor(v1, o, 64);
        v2 += __shfl_xor(v2, o, 64);
    }
    const int wid = t >> 6;
    if ((t & 63) == 0) {
        red[wid*3+0] = v0; red[wid*3+1] = v1; red[wid*3+2] = v2;
    }
    __syncthreads();
    const float kn2 = red[0]+red[3]+red[6]+red[9];
    const float jf2 = red[1]+red[4]+red[7]+red[10];
    const float kjg = red[2]+red[5]+red[8]+red[11];
    const float knorm = sqrtf(kn2);
    const float kn4 = kn2*kn2, kn8 = kn4*kn4;
    const float c1 = sqrtf(jf2) - 60.0f*kn8*knorm;
    const float c2 = kjg - 20.0f*kn8*kn2;
    const float scale = ((c1 > 1e-8f) || (c2 < -1e-8f)) ? 0.5f : 1.0f;
    out[b*N_+t] = (af+ag)*scale;
}

extern "C" void kernel_launch(void* const* d_in, const int* in_sizes, int n_in,
                              void* d_out, int out_size, void* d_ws, size_t ws_size,
                              hipStream_t stream) {
    const float* x    = (const float*)d_in[1];
    const float* Wf1  = (const float*)d_in[2];
    const float* bf1v = (const float*)d_in[3];
    const float* Wf2  = (const float*)d_in[4];
    const float* bf2v = (const float*)d_in[5];
    const float* Wg1  = (const float*)d_in[6];
    const float* bg1v = (const float*)d_in[7];
    const float* Wg2  = (const float*)d_in[8];
    const float* bg2v = (const float*)d_in[9];
    const float* Wk1  = (const float*)d_in[10];
    const float* bk1v = (const float*)d_in[11];
    const float* Wk2  = (const float*)d_in[12];
    const float* bk2v = (const float*)d_in[13];
    float* out = (float*)d_out;

    if (ws_size < (size_t)WS_FLOATS * sizeof(float)) {
        manifold_fused<<<BS_, 256, 0, stream>>>(
            x, Wf1, bf1v, Wf2, bf2v, Wg1, bg1v, Wg2, bg2v,
            Wk1, bk1v, Wk2, bk2v, out);
        return;
    }

    float* ws    = (float*)d_ws;
    float* sk    = ws + WS_SK;
    float* oacc  = ws + WS_OACC;
    float* opart = ws + WS_OPART;
    float* jpart = ws + WS_JPART;

    k12_l1l2  <<<384, 256, 0, stream>>>(x, Wf1, bf1v, Wg1, bg1v, Wk1, bk1v,
                                        Wf2, bf2v, Wg2, bg2v, Wk2, bk2v,
                                        sk, opart);
    k25_reduce<<<384, 256, 0, stream>>>(opart, oacc);
    k3_vj     <<<512, 256, 0, stream>>>(Wk1, Wk2, oacc, sk, jpart);
    k4_final  <<<BS_, 256, 0, stream>>>(oacc, jpart, out);
}